// Round 5
// baseline (155.909 us; speedup 1.0000x reference)
//
#include <hip/hip_runtime.h>
#include <stdint.h>
#include <math.h>

#define TPB1  64     // stage1: one wave per block = one slice-task, barrier-free
#define TPB2  512    // stage2: 8-wave block (R8 form, measured)
#define KTOP  100
#define K1    128    // selection rank cut (per-slice in s1, per-image in s2)
#define KSLOT 192    // per-slice emitted u32 slots (>= K1 + tie-bin margin)
#define CAP   768    // stage-1 survivor capacity (expected ~450/slice, +13 sigma)
#define SR    8      // slice rows
#define AMB   320    // per-wave ambiguous-tie queue (expected ~192, +9.5 sigma; inline fallback)

#define HB 272
#define WB 480
#define NSB 34       // 272/8
#define HP 68
#define WP 120
#define NSP 9        // ceil(68/8), last slice 4 rows
#define NB 64
#define NTB (NSB*NB)     // 2176 ball slice-tasks
#define NTP (NSP*NB)     // 576 player slice-tasks
#define NTASK (NTB+NTP)  // 2752 = 2752 blocks of 1 wave

// ============================================================================
// Validated invariants (prior session, absmax 0.0):
//  - np-f32 softmax p is a MONOTONE function G of D = fl32(x1-x0);
//    G collapse window |dD| < ~6e-8*e^|D| (< 0.25 for |D| < 13).
//  - NMS: keep iff p >= all 8 neighbors; D-space fast path + exact G on ties.
//  - top-k tie order: (p desc, idx asc)  ==  u64 key (p_bits<<32 | ~idx) desc.
//  - 16-bit D-key rank-128 cut contains the exact top-100 set.
// Measured ablations: stage1 NOT VALU-bound (R6), NOT atomic-bound (R7),
// NOT BW/LDS/bank-bound (counters), persistent blocks WORSE (R9).
// R10: test of the remaining theory (9-barrier x 8-wave convoy overhead):
//  stage1 rewritten wave-autonomous. One wave per slice, zero __syncthreads:
//  - NMS via register-rolling rows; col-max3 + 2 shfl per cell; 62-col strips
//    with 1-col shfl halos; 1-row global-load lookahead.
//  - positions via uniform ballot-prefix (no atomics); wave-private LDS hist;
//    suffix-scan + bin-pick fully in registers (shfl).
//  - ambiguous ties deferred to per-wave LDS queue, resolved densely at end
//    (bit-identical decision; inline fallback on overflow).
//  Stage2 = R8 exactly (clustered lvl-1 hist + rank-by-counting, measured -7us).
// ============================================================================
__device__ __forceinline__ float G_exact(float D) {
    float t = -fabsf(D);
    float etf = (float)exp((double)t);       // correctly-rounded f32 exp
    return (D > 0.0f) ? __fdiv_rn(1.0f, __fadd_rn(etf, 1.0f))
                      : __fdiv_rn(etf, __fadd_rn(1.0f, etf));
}

__device__ __forceinline__ uint32_t flip_f32(float D) {
    uint32_t u = __float_as_uint(D);
    return (u & 0x80000000u) ? ~u : (u | 0x80000000u);
}

// ---------------- stage 1 (wave-autonomous) ---------------------------------

// Guarded row-pair load: lane's (x0,x1) at (r,col); OOB -> (0, -inf) so
// D = x1-x0 = -inf.
template<int H, int W>
__device__ __forceinline__ void ldrow(const float* __restrict__ x0,
                                      const float* __restrict__ x1,
                                      int r, int col, bool colok,
                                      float& a, float& c) {
    if (r >= 0 && r < H && colok) {
        int o = r * W + col;
        a = x0[o]; c = x1[o];
    } else { a = 0.f; c = -INFINITY; }
}

// Register suffix-scan + pick over a 256-bin wave-private LDS histogram.
// Lane owns bins 4l..4l+3. Returns total, and the bin where suffix crosses kk
// (si >= kk && sn < kk) with its sn. Pure wave code, no barriers.
__device__ __forceinline__ void wave_pick(const uint32_t* h, uint32_t kk, int lane,
                                          uint32_t& total, uint32_t& obin, uint32_t& osn)
{
    uint32_t h0 = h[4*lane+0], h1 = h[4*lane+1], h2 = h[4*lane+2], h3 = h[4*lane+3];
    uint32_t tot = h0 + h1 + h2 + h3;
    uint32_t run = tot;
    #pragma unroll
    for (int d = 1; d < 64; d <<= 1) {
        uint32_t o = __shfl_down(run, d, 64);
        if (lane + d < 64) run += o;
    }
    uint32_t ab = run - tot;                 // suffix strictly above lane's bins
    uint32_t S3 = ab + h3, S2 = S3 + h2, S1 = S2 + h1, S0 = S1 + h0;
    uint32_t Sn = __shfl_down(S0, 1, 64);    // suffix at bin 4(l+1)
    if (lane == 63) Sn = 0;
    total = (uint32_t)__shfl((int)run, 0, 64);
    int fb = -1; uint32_t fs = 0;
    if (S0 >= kk && S1 < kk) { fb = 4*lane+0; fs = S1; }
    if (S1 >= kk && S2 < kk) { fb = 4*lane+1; fs = S2; }
    if (S2 >= kk && S3 < kk) { fb = 4*lane+2; fs = S3; }
    if (S3 >= kk && Sn < kk) { fb = 4*lane+3; fs = Sn; }
    uint64_t fm = __ballot(fb >= 0);
    if (fm) {
        int lead = __ffsll((unsigned long long)fm) - 1;
        obin = (uint32_t)__shfl(fb, lead, 64);
        osn  = (uint32_t)__shfl((int)fs, lead, 64);
    } else { obin = 0; osn = 0; }
}

// One slice-task, executed by one 64-lane wave. No __syncthreads anywhere.
template<int H, int W, int NS>
__device__ __forceinline__ void s1_wave(const float* __restrict__ x, int s, int b,
                                        uint32_t* __restrict__ key_out,
                                        uint32_t* hist, uint32_t* hist2,
                                        uint32_t* surv, uint32_t* outb,
                                        uint32_t* ambp, float* ambv, float* ambm)
{
    const int lane = threadIdx.x;
    const uint64_t lt = (1ull << lane) - 1ull;
    // zero wave-private scratch (far from later reuse; same-wave DS in-order)
    #pragma unroll
    for (int i = 0; i < 4; ++i) { hist[lane+64*i] = 0; hist2[lane+64*i] = 0; }
    outb[lane] = 0; outb[lane+64] = 0; outb[lane+128] = 0;

    const float* x0 = x + (size_t)b * 2 * H * W;
    const float* x1 = x0 + (size_t)H * W;
    const int r0 = s * SR;
    const int rows = (H - r0 < SR) ? (H - r0) : SR;
    constexpr int NSTR = (W + 61) / 62;      // 62 output cols per strip

    int cnt = 0, aCnt = 0;

    for (int st = 0; st < NSTR; ++st) {
        const int col = st * 62 - 1 + lane;              // -1: left halo lane
        const bool colok = (unsigned)col < (unsigned)W;
        const bool active = (lane >= 1) && (lane <= 62) && colok;

        float aP,cP,aC,cC,aN,cN,aX,cX;
        ldrow<H,W>(x0,x1, r0-1, col, colok, aP,cP);
        ldrow<H,W>(x0,x1, r0,   col, colok, aC,cC);
        ldrow<H,W>(x0,x1, r0+1, col, colok, aN,cN);
        ldrow<H,W>(x0,x1, r0+2, col, colok, aX,cX);      // 1-row lookahead
        float dP = __fsub_rn(cP,aP), dC = __fsub_rn(cC,aC), dN = __fsub_rn(cN,aN);

        for (int lr = 0; lr < rows; ++lr) {
            // 8-neighbor max: column max3 (this col, rows r-1..r+1) shuffled
            // from +-1 lanes, + own-column vertical pair.
            float m3  = fmaxf(fmaxf(dP, dC), dN);
            float m3l = __shfl(m3, (lane+63)&63, 64);
            float m3r = __shfl(m3, (lane+1)&63, 64);
            float mx  = fmaxf(fmaxf(m3l, m3r), fmaxf(dP, dN));
            float v   = dC;
            bool keep = false, amb = false;
            if (active) {
                if (v >= mx) keep = true;                               // exact
                else if (mx - v >= 0.25f && mx < 13.0f) keep = false;   // distinct
                else amb = true;                                        // defer
            }
            uint64_t am = __ballot(amb);
            if (amb) {
                int q = aCnt + (int)__popcll(am & lt);
                if (q < AMB) {
                    ambp[q] = ((uint32_t)lr << 9) | (uint32_t)col;
                    ambv[q] = v; ambm[q] = mx;
                } else keep = (G_exact(v) == G_exact(mx));  // overflow fallback
            }
            aCnt += (int)__popcll(am);
            uint64_t km = __ballot(keep);
            if (keep) {
                uint32_t key16 = flip_f32(v) >> 16;
                int pos = cnt + (int)__popcll(km & lt);
                if (pos < CAP)
                    surv[pos] = (key16 << 16) | ((uint32_t)lr << 9) | (uint32_t)col;
                atomicAdd(&hist[key16 >> 8], 1u);
            }
            cnt += (int)__popcll(km);
            if (lr + 1 < rows) {
                dP = dC; dC = dN;
                dN = __fsub_rn(cX, aX);
                if (lr + 3 <= rows)                       // last needed: r0+rows
                    ldrow<H,W>(x0,x1, r0+lr+3, col, colok, aX,cX);
            }
        }
    }

    // Dense resolution of deferred ties (all lanes active, ~3 iterations).
    const int na = (aCnt < AMB) ? aCnt : AMB;
    for (int t0 = 0; t0 < na; t0 += 64) {
        int i = t0 + lane;
        bool act = i < na;
        int ii = act ? i : 0;
        float v = ambv[ii], mxx = ambm[ii];
        bool keep = act && (G_exact(v) == G_exact(mxx));
        uint64_t km = __ballot(keep);
        if (keep) {
            uint32_t key16 = flip_f32(v) >> 16;
            int pos = cnt + (int)__popcll(km & lt);
            if (pos < CAP) surv[pos] = (key16 << 16) | ambp[ii];
            atomicAdd(&hist[key16 >> 8], 1u);
        }
        cnt += (int)__popcll(km);
    }
    const int n = (cnt < CAP) ? cnt : CAP;

    // Two-level D16 select, fully wave-local.
    uint32_t T16 = 0, total, b3, sn1;
    wave_pick(hist, K1, lane, total, b3, sn1);
    if (total >= K1) {
        uint32_t k2 = K1 - sn1;
        for (int t0 = 0; t0 < n; t0 += 64) {
            int i = t0 + lane;
            if (i < n) {
                uint32_t sv = surv[i];
                if ((sv >> 24) == b3) atomicAdd(&hist2[(sv >> 16) & 255u], 1u);
            }
        }
        uint32_t tot2, b2, sn2;
        wave_pick(hist2, k2, lane, tot2, b2, sn2);
        T16 = (b3 << 8) | b2;
    }

    // Compact survivors (D16 >= T16) into pre-zeroed outb, then emit.
    int out = 0;
    for (int t0 = 0; t0 < n; t0 += 64) {
        int i = t0 + lane;
        bool take = (i < n) && ((surv[i] >> 16) >= T16);
        uint64_t tm = __ballot(take);
        if (take) {
            int pos = out + (int)__popcll(tm & lt);
            if (pos < KSLOT) outb[pos] = surv[i];
        }
        out += (int)__popcll(tm);
    }
    uint32_t* ko = key_out + ((size_t)b * NS + s) * KSLOT;
    ko[lane] = outb[lane];
    ko[lane+64] = outb[lane+64];
    ko[lane+128] = outb[lane+128];
}

__global__ __launch_bounds__(TPB1) void stage1(const float* __restrict__ bmap,
                                               const float* __restrict__ pmap,
                                               uint32_t* __restrict__ bkey,
                                               uint32_t* __restrict__ pkey)
{
    extern __shared__ unsigned char smem[];
    uint32_t* hist  = (uint32_t*)smem;      // 256
    uint32_t* hist2 = hist + 256;           // 256
    uint32_t* surv  = hist2 + 256;          // CAP
    uint32_t* outb  = surv + CAP;           // KSLOT
    uint32_t* ambp  = outb + KSLOT;         // AMB
    float*    ambv  = (float*)(ambp + AMB); // AMB
    float*    ambm  = ambv + AMB;           // AMB

    const int task = blockIdx.x;
    if (task < NTB) {
        int b = task / NSB, s = task - b * NSB;
        s1_wave<HB, WB, NSB>(bmap, s, b, bkey, hist, hist2, surv, outb, ambp, ambv, ambm);
    } else {
        int t = task - NTB;
        int b = t / NSP, s = t - b * NSP;
        s1_wave<HP, WP, NSP>(pmap, s, b, pkey, hist, hist2, surv, outb, ambp, ambv, ambm);
    }
}

// ---------------- stage 2 (R8 form, unchanged) ------------------------------
__device__ __forceinline__ int agg_push(int* ctr, bool active) {
    uint64_t m = __ballot(active);
    int pos = -1;
    if (active) {
        int lane = threadIdx.x & 63;
        int lead = __ffsll((unsigned long long)m) - 1;
        int before = (int)__popcll(m & ((1ull << lane) - 1ull));
        int base = 0;
        if (lane == lead) base = atomicAdd(ctr, (int)__popcll(m));
        base = __shfl(base, lead, 64);
        pos = base + before;
    }
    return pos;
}

__device__ __forceinline__ void hist_clustered(uint32_t* hist, uint32_t bin, bool active) {
    uint64_t todo = __ballot(active);
    while (todo) {
        int lead = __ffsll((unsigned long long)todo) - 1;
        uint32_t b = (uint32_t)__shfl((int)bin, lead, 64);
        uint64_t same = __ballot(active && (bin == b));
        if ((int)(threadIdx.x & 63) == lead) atomicAdd(&hist[b], (uint32_t)__popcll(same));
        todo &= ~same;
    }
}

__device__ __forceinline__ void suffix_scan_256(uint32_t* hist) {
    if (threadIdx.x < 64) {
        int lane = threadIdx.x;
        uint32_t h0 = hist[4*lane+0], h1 = hist[4*lane+1];
        uint32_t h2 = hist[4*lane+2], h3 = hist[4*lane+3];
        uint32_t tot = h0 + h1 + h2 + h3;
        uint32_t run = tot;
        #pragma unroll
        for (int d = 1; d < 64; d <<= 1) {
            uint32_t o = __shfl_down(run, d, 64);
            if (lane + d < 64) run += o;
        }
        uint32_t ab = run - tot;
        hist[4*lane+3] = ab + h3;
        hist[4*lane+2] = ab + h3 + h2;
        hist[4*lane+1] = ab + h3 + h2 + h1;
        hist[4*lane+0] = ab + tot;
    }
    __syncthreads();
}

template<int H, int W, int NS, bool BALL>
__device__ __forceinline__ void stage2_impl(const float* __restrict__ xmap,
                                            const float* __restrict__ pbbox,
                                            const uint32_t* __restrict__ key_in,
                                            float* __restrict__ outp,
                                            int b, unsigned char* smem)
{
    constexpr int M = NS * KSLOT;
    const float* x0 = xmap + (size_t)b * 2 * H * W;
    const float* x1 = x0 + (size_t)H * W;
    const uint32_t* kin = key_in + (size_t)b * M;

    uint32_t* keys  = (uint32_t*)smem;           // M
    uint32_t* hist  = keys + M;                  // 256 (level-1)
    uint32_t* hist2 = hist + 256;                // 256 (level-2)
    uint32_t* rnk   = hist2 + 256;               // 256 (ranks)
    uint64_t* outb  = (uint64_t*)(rnk + 256);    // 256
    __shared__ int s_out;
    __shared__ uint32_t s_bin, s_ab, s_bin2, s_none;
    if (threadIdx.x == 0) { s_out = 0; s_none = 0; }
    if (threadIdx.x < 256) {
        hist[threadIdx.x] = 0; hist2[threadIdx.x] = 0;
        rnk[threadIdx.x] = 0; outb[threadIdx.x] = 0;
    }
    for (int t = threadIdx.x; t < KTOP * 5; t += TPB2) outp[t] = 0.f;
    __syncthreads();

    for (int t = threadIdx.x; t < M; t += TPB2) {
        uint32_t k = kin[t];
        keys[t] = k;
        hist_clustered(hist, k >> 24, k != 0);
    }
    __syncthreads();
    suffix_scan_256(hist);
    if (threadIdx.x < 256) {
        uint32_t si = hist[threadIdx.x];
        uint32_t sn = (threadIdx.x < 255) ? hist[threadIdx.x + 1] : 0u;
        if (threadIdx.x == 0 && si < K1) s_none = 1;
        if (si >= K1 && sn < K1) { s_bin = threadIdx.x; s_ab = sn; }
    }
    __syncthreads();

    uint32_t T16 = 0;
    if (!s_none) {
        const uint32_t b3 = s_bin;
        const uint32_t k2 = K1 - s_ab;
        for (int t = threadIdx.x; t < M; t += TPB2) {
            uint32_t k = keys[t];
            if (k && (k >> 24) == b3) atomicAdd(&hist2[(k >> 16) & 255u], 1u);
        }
        __syncthreads();
        suffix_scan_256(hist2);
        if (threadIdx.x < 256) {
            uint32_t si = hist2[threadIdx.x];
            uint32_t sn = (threadIdx.x < 255) ? hist2[threadIdx.x + 1] : 0u;
            if (si >= k2 && sn < k2) s_bin2 = threadIdx.x;
        }
        __syncthreads();
        T16 = (b3 << 8) | s_bin2;
    }

    for (int t = threadIdx.x; t < M; t += TPB2) {
        uint32_t k = keys[t];
        bool take = (k != 0) && ((k >> 16) >= T16);
        int pos = agg_push(&s_out, take);
        if (take && pos < 256) {
            int sIdx = t / KSLOT;
            int lr = (k >> 9) & 7, c = k & 511;
            int gidx = (sIdx * SR + lr) * W + c;
            float D = __fsub_rn(x1[gidx], x0[gidx]);
            float p = G_exact(D);
            outb[pos] = ((uint64_t)__float_as_uint(p) << 32) | (uint32_t)(~gidx);
        }
    }
    __syncthreads();

    {
        int i = threadIdx.x & 255;
        int half = threadIdx.x >> 8;
        uint64_t ki = outb[i];
        uint32_t cnt = 0;
        int j0 = half * 128;
        #pragma unroll 4
        for (int j = j0; j < j0 + 128; ++j) cnt += (outb[j] > ki) ? 1u : 0u;
        atomicAdd(&rnk[i], cnt);
    }
    __syncthreads();

    if (threadIdx.x < 256) {
        uint64_t k = outb[threadIdx.x];
        uint32_t r = rnk[threadIdx.x];
        if (k != 0 && r < KTOP) {
            int id = (int)(~(uint32_t)k);
            float val = __uint_as_float((uint32_t)(k >> 32));
            int yy = id / W, xx = id - yy * W;
            constexpr float ds = BALL ? 4.0f : 16.0f;
            float xc = (float)xx * ds + (ds - 1.0f) * 0.5f;
            float yc = (float)yy * ds + (ds - 1.0f) * 0.5f;
            float t0 = 0.f, t1 = 0.f;
            float t2 = BALL ? 40.0f : 0.0f, t3 = BALL ? 40.0f : 0.0f;
            if (!BALL) {
                const float* bb = pbbox + (size_t)b * 4 * H * W;
                constexpr float sx = (float)W * ds, sy = (float)H * ds;
                t0 = bb[id]             * sx;
                t1 = bb[id + H * W]     * sy;
                t2 = bb[id + 2 * H * W] * sx;
                t3 = bb[id + 3 * H * W] * sy;
            }
            float bx = xc + t0, by = yc + t1;
            float* op = outp + (size_t)r * 5;
            op[0] = bx - 0.5f * t2;
            op[1] = by - 0.5f * t3;
            op[2] = bx + 0.5f * t2;
            op[3] = by + 0.5f * t3;
            op[4] = val;
        }
    }
}

__global__ __launch_bounds__(TPB2) void stage2(const float* __restrict__ bmap,
                                               const float* __restrict__ pmap,
                                               const float* __restrict__ pbbox,
                                               const uint32_t* __restrict__ bkey,
                                               const uint32_t* __restrict__ pkey,
                                               float* __restrict__ out)
{
    extern __shared__ unsigned char smem[];
    if (blockIdx.x < NB) {
        int b = blockIdx.x;
        stage2_impl<HB, WB, NSB, true>(bmap, nullptr, bkey,
            out + (size_t)NB * KTOP * 5 + (size_t)b * KTOP * 5, b, smem);
    } else {
        int b = blockIdx.x - NB;
        stage2_impl<HP, WP, NSP, false>(pmap, pbbox, pkey,
            out + (size_t)b * KTOP * 5, b, smem);
    }
}

// ---- launch -----------------------------------------------------------------
extern "C" void kernel_launch(void* const* d_in, const int* in_sizes, int n_in,
                              void* d_out, int out_size, void* d_ws, size_t ws_size,
                              hipStream_t stream) {
    const float* pmap  = (const float*)d_in[0];   // [64,2,68,120]
    const float* pbbox = (const float*)d_in[1];   // [64,4,68,120]
    const float* bmap  = (const float*)d_in[2];   // [64,2,272,480]
    float* out = (float*)d_out;                   // player [64,100,5] then ball

    uint32_t* ws_bkey = (uint32_t*)d_ws;                       // 64*34*192 u32
    uint32_t* ws_pkey = ws_bkey + (size_t)NB * NSB * KSLOT;    // 64*9*192 u32
    // total ws: 2,113,536 B (within proven budget)

    // stage1 LDS per wave-block: hist 1024 + hist2 1024 + surv 3072 +
    //   outb 768 + amb 320*(4+4+4) = 9728 B
    size_t lds1 = 2048 + (size_t)CAP * 4 + (size_t)KSLOT * 4 + (size_t)AMB * 12;
    stage1<<<dim3(NTASK), TPB1, lds1, stream>>>(bmap, pmap, ws_bkey, ws_pkey);

    // LDS: keys 26112 + hist 1024 + hist2 1024 + rnk 1024 + outb 2048 = 31232 B
    size_t lds2 = (size_t)NSB * KSLOT * 4 + 3072 + 2048;
    stage2<<<2 * NB, TPB2, lds2, stream>>>(bmap, pmap, pbbox, ws_bkey, ws_pkey, out);
}

// Round 8
// 141.432 us; speedup vs baseline: 1.1024x; 1.1024x over previous
//
#include <hip/hip_runtime.h>
#include <stdint.h>
#include <math.h>

#define TPB1  256    // stage1: 4 waves/block, 6 blocks/CU (LDS-limited) -> 24 waves
#define TPB2  512    // stage2: 8 waves (rank pass needs >=512 threads)
#define KTOP  100
#define K1    128    // selection rank cut (per-slice in s1, per-image in s2)
#define KSLOT 192    // per-slice emitted u32 slots (>= K1 + tie-bin margin)
#define CAP   768    // stage-1 survivor capacity (expected ~450/slice, +13 sigma)
#define SR    8      // slice rows

#define HB 272
#define WB 480
#define NSB 34       // 272/8
#define HP 68
#define WP 120
#define NSP 9        // ceil(68/8), last slice 4 rows
#define NB 64

// ============================================================================
// Validated invariants (prior session, absmax 0.0):
//  - np-f32 softmax p is a MONOTONE function G of D = fl32(x1-x0);
//    G collapse window |dD| < ~6e-8*e^|D| (< 0.25 for |D| < 13).
//  - NMS: keep iff p >= all 8 neighbors; D-space fast path + exact G on ties.
//  - top-k tie order: (p desc, idx asc)  ==  u64 key (p_bits<<32 | ~idx) desc.
//  - 16-bit D-key rank-128 cut contains the exact top-100 set.
// Structural ablations (measured): stage1 NOT VALU-bound (R6), NOT
// atomic-bound (R7), persistent blocks WORSE (R9), wave-autonomous WORSE
// (R10). Fused single-launch (R11/R12) -> container failed twice, abandoned.
// R13: R8 split path (last passing, 139.4us) with ONE untested parameter:
//  stage1 at TPB=256. At 512, LDS (25088B) + 32-wave cap pin 4 blk/CU with
//  8-wave barrier convoys; at 256 -> 6 blk/CU, 4-wave convoys, 1.8 vs 2.7
//  scheduling rounds. Tests the last convoy-overlap hypothesis with a
//  minimal, correctness-identical diff. Stage2 = R8 verbatim.
// ============================================================================
__device__ __forceinline__ float G_exact(float D) {
    float t = -fabsf(D);
    float etf = (float)exp((double)t);       // correctly-rounded f32 exp
    return (D > 0.0f) ? __fdiv_rn(1.0f, __fadd_rn(etf, 1.0f))
                      : __fdiv_rn(etf, __fadd_rn(1.0f, etf));
}

__device__ __forceinline__ uint32_t flip_f32(float D) {
    uint32_t u = __float_as_uint(D);
    return (u & 0x80000000u) ? ~u : (u | 0x80000000u);
}

// Wave-aggregated counter push (stage2 only: low-frequency call sites).
__device__ __forceinline__ int agg_push(int* ctr, bool active) {
    uint64_t m = __ballot(active);
    int pos = -1;
    if (active) {
        int lane = threadIdx.x & 63;
        int lead = __ffsll((unsigned long long)m) - 1;
        int before = (int)__popcll(m & ((1ull << lane) - 1ull));
        int base = 0;
        if (lane == lead) base = atomicAdd(ctr, (int)__popcll(m));
        base = __shfl(base, lead, 64);
        pos = base + before;
    }
    return pos;
}

// Clustered histogram add (stage2 load pass only): one atomicAdd per
// DISTINCT bin per wave.
__device__ __forceinline__ void hist_clustered(uint32_t* hist, uint32_t bin, bool active) {
    uint64_t todo = __ballot(active);
    while (todo) {
        int lead = __ffsll((unsigned long long)todo) - 1;
        uint32_t b = (uint32_t)__shfl((int)bin, lead, 64);
        uint64_t same = __ballot(active && (bin == b));
        if ((int)(threadIdx.x & 63) == lead) atomicAdd(&hist[b], (uint32_t)__popcll(same));
        todo &= ~same;
    }
}

// In-place suffix-sum of 256 u32 bins: hist[i] <- sum_{j>=i} hist[j].
// Wave 0 via shuffles; ends with a barrier. (validated)
__device__ __forceinline__ void suffix_scan_256(uint32_t* hist) {
    if (threadIdx.x < 64) {
        int lane = threadIdx.x;
        uint32_t h0 = hist[4*lane+0], h1 = hist[4*lane+1];
        uint32_t h2 = hist[4*lane+2], h3 = hist[4*lane+3];
        uint32_t tot = h0 + h1 + h2 + h3;
        uint32_t run = tot;
        #pragma unroll
        for (int d = 1; d < 64; d <<= 1) {
            uint32_t o = __shfl_down(run, d, 64);
            if (lane + d < 64) run += o;
        }
        uint32_t ab = run - tot;
        hist[4*lane+3] = ab + h3;
        hist[4*lane+2] = ab + h3 + h2;
        hist[4*lane+1] = ab + h3 + h2 + h1;
        hist[4*lane+0] = ab + tot;
    }
    __syncthreads();
}

// 6-wide row window [c4-1 .. c4+4] from the LDS D-tile (OOB -> -inf).
template<int W>
__device__ __forceinline__ void row6(const float* df, int row, int c4, float* a) {
    const float4 m = ((const float4*)df)[(row * W + c4) >> 2];
    a[1] = m.x; a[2] = m.y; a[3] = m.z; a[4] = m.w;
    a[0] = (c4 > 0)     ? df[row * W + c4 - 1] : -INFINITY;
    a[5] = (c4 + 4 < W) ? df[row * W + c4 + 4] : -INFINITY;
}

// ---- stage 1 body: NMS + D16 radix-select, emit u32 slots (R8 form) --------
// Requires blockDim.x == TPB1 >= 256.
template<int H, int W, int NS>
__device__ __forceinline__ void stage1_impl(const float* __restrict__ x,
                                            int s, int b,
                                            uint32_t* __restrict__ key_out,
                                            unsigned char* smem)
{
    constexpr int W4 = W / 4;
    constexpr int tileRows = SR + 2;
    const int r0 = s * SR;
    const int rows = (H - r0 < SR) ? (H - r0) : SR;

    float*    df    = (float*)smem;                        // tileRows * W
    uint32_t* surv  = (uint32_t*)(df + tileRows * W);      // CAP
    uint32_t* hist  = surv + CAP;                          // 256
    uint32_t* hist2 = hist + 256;                          // 256 (level-2)
    uint32_t* outb  = hist2 + 256;                         // KSLOT
    __shared__ int s_cnt, s_out;
    __shared__ uint32_t s_bin, s_ab, s_bin2, s_none;
    if (threadIdx.x == 0) { s_cnt = 0; s_out = 0; s_none = 0; }
    if (threadIdx.x < 256) { hist[threadIdx.x] = 0; hist2[threadIdx.x] = 0; }
    if (threadIdx.x < KSLOT) outb[threadIdx.x] = 0;

    const float*  x0  = x + (size_t)b * 2 * H * W;
    const float*  x1  = x0 + (size_t)H * W;
    const float4* x0v = (const float4*)x0;
    const float4* x1v = (const float4*)x1;
    float4* dfv = (float4*)df;

    // D tile (rows r0-1 .. r0+SR), float4-vectorized; OOB rows -> -inf.
    constexpr int nt4 = tileRows * W4;
    for (int t = threadIdx.x; t < nt4; t += TPB1) {
        int tr = t / W4, c4 = t - tr * W4;        // compile-time divisor
        int r = r0 - 1 + tr;
        float4 d4 = make_float4(-INFINITY, -INFINITY, -INFINITY, -INFINITY);
        if (r >= 0 && r < H) {
            float4 a = x0v[r * W4 + c4];
            float4 c = x1v[r * W4 + c4];
            d4.x = __fsub_rn(c.x, a.x);
            d4.y = __fsub_rn(c.y, a.y);
            d4.z = __fsub_rn(c.z, a.z);
            d4.w = __fsub_rn(c.w, a.w);
        }
        dfv[t] = d4;
    }
    __syncthreads();

    // NMS (4 cells/iter) + level-1 histogram fused into the keep path.
    const int groups = rows * W4;
    for (int g = threadIdx.x; g < groups; g += TPB1) {
        int lr = g / W4, c4 = (g - lr * W4) << 2; // compile-time divisor
        int tr = lr + 1;
        float ap[6], ac[6], an[6];
        row6<W>(df, tr - 1, c4, ap);
        row6<W>(df, tr,     c4, ac);
        row6<W>(df, tr + 1, c4, an);
        #pragma unroll
        for (int j = 0; j < 4; ++j) {
            float v = ac[j + 1];
            float mx = fmaxf(fmaxf(fmaxf(ap[j], ap[j+1]), fmaxf(ap[j+2], an[j])),
                             fmaxf(fmaxf(an[j+1], an[j+2]), fmaxf(ac[j], ac[j+2])));
            bool keep;
            if (v >= mx) keep = true;                              // exact
            else if (mx - v >= 0.25f && mx < 13.0f) keep = false;  // G distinct
            else keep = (G_exact(v) == G_exact(mx));               // rare tie
            if (keep) {
                uint32_t key16 = flip_f32(v) >> 16;
                int pos = atomicAdd(&s_cnt, 1);
                if (pos < CAP)
                    surv[pos] = (key16 << 16) | ((uint32_t)lr << 9) | (uint32_t)(c4 + j);
                atomicAdd(&hist[key16 >> 8], 1u);
            }
        }
    }
    __syncthreads();
    const int n = (s_cnt < CAP) ? s_cnt : CAP;

    // Level-1 select on D16 high byte.
    suffix_scan_256(hist);
    if (threadIdx.x < 256) {
        uint32_t si = hist[threadIdx.x];
        uint32_t sn = (threadIdx.x < 255) ? hist[threadIdx.x + 1] : 0u;
        if (threadIdx.x == 0 && si < K1) s_none = 1;
        if (si >= K1 && sn < K1) { s_bin = threadIdx.x; s_ab = sn; }
    }
    __syncthreads();

    uint32_t T16 = 0;
    if (!s_none) {
        const uint32_t b3 = s_bin;
        const uint32_t k2 = K1 - s_ab;
        // Level-2: hist2 pre-zeroed in the init phase (no rezero barrier).
        for (int t = threadIdx.x; t < n; t += TPB1) {
            uint32_t sv = surv[t];
            if ((sv >> 24) == b3) atomicAdd(&hist2[(sv >> 16) & 255u], 1u);
        }
        __syncthreads();
        suffix_scan_256(hist2);
        if (threadIdx.x < 256) {
            uint32_t si = hist2[threadIdx.x];
            uint32_t sn = (threadIdx.x < 255) ? hist2[threadIdx.x + 1] : 0u;
            if (si >= k2 && sn < k2) s_bin2 = threadIdx.x;
        }
        __syncthreads();
        T16 = (b3 << 8) | s_bin2;
    }

    // Compact survivors with D16 >= T16 (unsorted) into pre-zeroed outb.
    for (int t = threadIdx.x; t < n; t += TPB1) {
        uint32_t sv = surv[t];
        if ((sv >> 16) >= T16) {
            int pos = atomicAdd(&s_out, 1);
            if (pos < KSLOT) outb[pos] = sv;
        }
    }
    __syncthreads();
    if (threadIdx.x < KSLOT)
        key_out[((size_t)b * NS + s) * KSLOT + threadIdx.x] = outb[threadIdx.x];
}

// ---- stage 2 body: D16 select -> exact-p re-rank of <=256 -> decode (R8) ---
// Requires blockDim.x == TPB2 == 512 (rank pass uses tid>>8).
template<int H, int W, int NS, bool BALL>
__device__ __forceinline__ void stage2_impl(const float* __restrict__ xmap,
                                            const float* __restrict__ pbbox,
                                            const uint32_t* __restrict__ key_in,
                                            float* __restrict__ outp,
                                            int b, unsigned char* smem)
{
    constexpr int M = NS * KSLOT;
    const float* x0 = xmap + (size_t)b * 2 * H * W;
    const float* x1 = x0 + (size_t)H * W;
    const uint32_t* kin = key_in + (size_t)b * M;

    uint32_t* keys  = (uint32_t*)smem;           // M
    uint32_t* hist  = keys + M;                  // 256 (level-1)
    uint32_t* hist2 = hist + 256;                // 256 (level-2)
    uint32_t* rnk   = hist2 + 256;               // 256 (ranks)
    uint64_t* outb  = (uint64_t*)(rnk + 256);    // 256
    __shared__ int s_out;
    __shared__ uint32_t s_bin, s_ab, s_bin2, s_none;
    if (threadIdx.x == 0) { s_out = 0; s_none = 0; }
    if (threadIdx.x < 256) {
        hist[threadIdx.x] = 0; hist2[threadIdx.x] = 0;
        rnk[threadIdx.x] = 0; outb[threadIdx.x] = 0;
    }
    // Defensive zero of the 100 output rows (rank-scatter fills real rows).
    for (int t = threadIdx.x; t < KTOP * 5; t += TPB2) outp[t] = 0.f;
    __syncthreads();

    // Load keys + level-1 histogram in one pass (clustered bin atomics).
    for (int t = threadIdx.x; t < M; t += TPB2) {
        uint32_t k = kin[t];
        keys[t] = k;
        hist_clustered(hist, k >> 24, k != 0);
    }
    __syncthreads();
    suffix_scan_256(hist);
    if (threadIdx.x < 256) {
        uint32_t si = hist[threadIdx.x];
        uint32_t sn = (threadIdx.x < 255) ? hist[threadIdx.x + 1] : 0u;
        if (threadIdx.x == 0 && si < K1) s_none = 1;
        if (si >= K1 && sn < K1) { s_bin = threadIdx.x; s_ab = sn; }
    }
    __syncthreads();

    uint32_t T16 = 0;
    if (!s_none) {
        const uint32_t b3 = s_bin;
        const uint32_t k2 = K1 - s_ab;
        // Level-2: hist2 pre-zeroed in the init phase.
        for (int t = threadIdx.x; t < M; t += TPB2) {
            uint32_t k = keys[t];
            if (k && (k >> 24) == b3) atomicAdd(&hist2[(k >> 16) & 255u], 1u);
        }
        __syncthreads();
        suffix_scan_256(hist2);
        if (threadIdx.x < 256) {
            uint32_t si = hist2[threadIdx.x];
            uint32_t sn = (threadIdx.x < 255) ? hist2[threadIdx.x + 1] : 0u;
            if (si >= k2 && sn < k2) s_bin2 = threadIdx.x;
        }
        __syncthreads();
        T16 = (b3 << 8) | s_bin2;
    }

    // Compact finalists into pre-zeroed outb; exact np p computed only here.
    for (int t = threadIdx.x; t < M; t += TPB2) {
        uint32_t k = keys[t];
        bool take = (k != 0) && ((k >> 16) >= T16);
        int pos = agg_push(&s_out, take);
        if (take && pos < 256) {
            int sIdx = t / KSLOT;                      // compile-time divisor
            int lr = (k >> 9) & 7, c = k & 511;
            int gidx = (sIdx * SR + lr) * W + c;
            float D = __fsub_rn(x1[gidx], x0[gidx]);
            float p = G_exact(D);
            outb[pos] = ((uint64_t)__float_as_uint(p) << 32) | (uint32_t)(~gidx);
        }
    }
    __syncthreads();

    // Rank-by-counting over unique u64 keys (2 barriers vs bitonic's 36).
    {
        int i = threadIdx.x & 255;
        int half = threadIdx.x >> 8;
        uint64_t ki = outb[i];
        uint32_t cnt = 0;
        int j0 = half * 128;
        #pragma unroll 4
        for (int j = j0; j < j0 + 128; ++j) cnt += (outb[j] > ki) ? 1u : 0u;
        atomicAdd(&rnk[i], cnt);
    }
    __syncthreads();

    // Decode: finalist with rank r < KTOP writes output row r directly.
    if (threadIdx.x < 256) {
        uint64_t k = outb[threadIdx.x];
        uint32_t r = rnk[threadIdx.x];
        if (k != 0 && r < KTOP) {
            int id = (int)(~(uint32_t)k);
            float val = __uint_as_float((uint32_t)(k >> 32));
            int yy = id / W, xx = id - yy * W;             // compile-time divisor
            constexpr float ds = BALL ? 4.0f : 16.0f;
            float xc = (float)xx * ds + (ds - 1.0f) * 0.5f;
            float yc = (float)yy * ds + (ds - 1.0f) * 0.5f;
            float t0 = 0.f, t1 = 0.f;
            float t2 = BALL ? 40.0f : 0.0f, t3 = BALL ? 40.0f : 0.0f;
            if (!BALL) {
                const float* bb = pbbox + (size_t)b * 4 * H * W;
                constexpr float sx = (float)W * ds, sy = (float)H * ds;
                t0 = bb[id]             * sx;
                t1 = bb[id + H * W]     * sy;
                t2 = bb[id + 2 * H * W] * sx;
                t3 = bb[id + 3 * H * W] * sy;
            }
            float bx = xc + t0, by = yc + t1;
            float* op = outp + (size_t)r * 5;
            op[0] = bx - 0.5f * t2;
            op[1] = by - 0.5f * t3;
            op[2] = bx + 0.5f * t2;
            op[3] = by + 0.5f * t3;
            op[4] = val;
        }
    }
}

__global__ __launch_bounds__(TPB1) void stage1(const float* __restrict__ bmap,
                                               const float* __restrict__ pmap,
                                               uint32_t* __restrict__ bkey,
                                               uint32_t* __restrict__ pkey)
{
    extern __shared__ unsigned char smem[];
    if (blockIdx.x < NSB)
        stage1_impl<HB, WB, NSB>(bmap, blockIdx.x, blockIdx.y, bkey, smem);
    else
        stage1_impl<HP, WP, NSP>(pmap, blockIdx.x - NSB, blockIdx.y, pkey, smem);
}

__global__ __launch_bounds__(TPB2) void stage2(const float* __restrict__ bmap,
                                               const float* __restrict__ pmap,
                                               const float* __restrict__ pbbox,
                                               const uint32_t* __restrict__ bkey,
                                               const uint32_t* __restrict__ pkey,
                                               float* __restrict__ out)
{
    extern __shared__ unsigned char smem[];
    if (blockIdx.x < NB) {
        int b = blockIdx.x;
        stage2_impl<HB, WB, NSB, true>(bmap, nullptr, bkey,
            out + (size_t)NB * KTOP * 5 + (size_t)b * KTOP * 5, b, smem);
    } else {
        int b = blockIdx.x - NB;
        stage2_impl<HP, WP, NSP, false>(pmap, pbbox, pkey,
            out + (size_t)b * KTOP * 5, b, smem);
    }
}

// ---- launch -----------------------------------------------------------------
extern "C" void kernel_launch(void* const* d_in, const int* in_sizes, int n_in,
                              void* d_out, int out_size, void* d_ws, size_t ws_size,
                              hipStream_t stream) {
    const float* pmap  = (const float*)d_in[0];   // [64,2,68,120]
    const float* pbbox = (const float*)d_in[1];   // [64,4,68,120]
    const float* bmap  = (const float*)d_in[2];   // [64,2,272,480]
    float* out = (float*)d_out;                   // player [64,100,5] then ball

    uint32_t* ws_bkey = (uint32_t*)d_ws;                       // 64*34*192 u32
    uint32_t* ws_pkey = ws_bkey + (size_t)NB * NSB * KSLOT;    // 64*9*192 u32
    // total ws: 2,113,536 B (within proven budget)

    // LDS: df 19200 + surv 3072 + hist 1024 + hist2 1024 + outb 768
    //    = 25088 B -> 6 blk/CU at TPB1=256 (24 waves/CU)
    size_t lds1 = (size_t)(SR + 2) * WB * 4 + (size_t)CAP * 4 + 2048 + (size_t)KSLOT * 4;
    stage1<<<dim3(NSB + NSP, NB), TPB1, lds1, stream>>>(bmap, pmap, ws_bkey, ws_pkey);

    // LDS: keys 26112 + hist 1024 + hist2 1024 + rnk 1024 + outb 2048 = 31232 B
    size_t lds2 = (size_t)NSB * KSLOT * 4 + 3072 + 2048;
    stage2<<<2 * NB, TPB2, lds2, stream>>>(bmap, pmap, pbbox, ws_bkey, ws_pkey, out);
}

// Round 9
// 128.054 us; speedup vs baseline: 1.2175x; 1.1045x over previous
//
#include <hip/hip_runtime.h>
#include <stdint.h>
#include <math.h>

#define TPB   512    // 8 waves/block -> 4 blocks/CU hits the 32-wave cap
#define KTOP  100
#define K1    128    // selection rank cut (per-slice in s1, per-image in s2)
#define KSLOT 192    // per-slice emitted u32 slots (>= K1 + tie-bin margin)
#define CAP   768    // stage-1 survivor capacity (expected ~450/slice, +13 sigma)
#define SR    8      // slice rows

#define HB 272
#define WB 480
#define NSB 34       // 272/8
#define HP 68
#define WP 120
#define NSP 9        // ceil(68/8), last slice 4 rows
#define NB 64

// ============================================================================
// Validated invariants (prior session, absmax 0.0):
//  - np-f32 softmax p is a MONOTONE function G of D = fl32(x1-x0);
//    G collapse window: for mx>0, ~6e-8*e^mx (= 2^-24 / (dp/dD), ulp(p)=2^-24
//    for p in [0.5,1)); for mx<=0, bounded by ~1e-6 (ulp(p)/[p(1-p)], p<=0.5).
//  - NMS: keep iff p >= all 8 neighbors; D-space fast path + exact G on ties.
//  - top-k tie order: (p desc, idx asc)  ==  u64 key (p_bits<<32 | ~idx) desc.
//  - 16-bit D-key rank-128 cut contains the exact top-100 set.
// Structural ablations (measured): stage1 NOT atomic-bound (R7), persistent
// blocks WORSE (R9), wave-autonomous WORSE (R10), TPB=256 neutral (R13),
// fused single-launch infra-failed twice (R11/R12). R6 measured the masked
// f64-exp tie path at ~half of VALU issue (VALUBusy 56->26 when deferred).
// R14: replace the fixed ambiguity window (mx-v < 0.25, ~5%/lane -> f64 path
//  on ~96% of wave-steps) with a scaled certificate:
//      distinct if  mx - v >= 4e-6 * e^max(mx,0)
//  (>=16x margin over the 6e-8*e^mx collapse window for mx>0, >=4x over the
//  4-ulp-budget ~1e-6 bound for mx<=0; no mx<13 cap needed -- expf overflow
//  fails the test conservatively). G_exact fallback shrinks to ~30 cells/run.
//  3 inline instrs (expf+mul+cmp), zero new sync. Config otherwise = R8 best.
// ============================================================================
__device__ __forceinline__ float G_exact(float D) {
    float t = -fabsf(D);
    float etf = (float)exp((double)t);       // correctly-rounded f32 exp
    return (D > 0.0f) ? __fdiv_rn(1.0f, __fadd_rn(etf, 1.0f))
                      : __fdiv_rn(etf, __fadd_rn(1.0f, etf));
}

__device__ __forceinline__ uint32_t flip_f32(float D) {
    uint32_t u = __float_as_uint(D);
    return (u & 0x80000000u) ? ~u : (u | 0x80000000u);
}

// Wave-aggregated counter push (stage2 only: low-frequency call sites).
__device__ __forceinline__ int agg_push(int* ctr, bool active) {
    uint64_t m = __ballot(active);
    int pos = -1;
    if (active) {
        int lane = threadIdx.x & 63;
        int lead = __ffsll((unsigned long long)m) - 1;
        int before = (int)__popcll(m & ((1ull << lane) - 1ull));
        int base = 0;
        if (lane == lead) base = atomicAdd(ctr, (int)__popcll(m));
        base = __shfl(base, lead, 64);
        pos = base + before;
    }
    return pos;
}

// Clustered histogram add (stage2 load pass only): one atomicAdd per
// DISTINCT bin per wave.
__device__ __forceinline__ void hist_clustered(uint32_t* hist, uint32_t bin, bool active) {
    uint64_t todo = __ballot(active);
    while (todo) {
        int lead = __ffsll((unsigned long long)todo) - 1;
        uint32_t b = (uint32_t)__shfl((int)bin, lead, 64);
        uint64_t same = __ballot(active && (bin == b));
        if ((int)(threadIdx.x & 63) == lead) atomicAdd(&hist[b], (uint32_t)__popcll(same));
        todo &= ~same;
    }
}

// In-place suffix-sum of 256 u32 bins: hist[i] <- sum_{j>=i} hist[j].
// Wave 0 via shuffles; ends with a barrier. (validated)
__device__ __forceinline__ void suffix_scan_256(uint32_t* hist) {
    if (threadIdx.x < 64) {
        int lane = threadIdx.x;
        uint32_t h0 = hist[4*lane+0], h1 = hist[4*lane+1];
        uint32_t h2 = hist[4*lane+2], h3 = hist[4*lane+3];
        uint32_t tot = h0 + h1 + h2 + h3;
        uint32_t run = tot;
        #pragma unroll
        for (int d = 1; d < 64; d <<= 1) {
            uint32_t o = __shfl_down(run, d, 64);
            if (lane + d < 64) run += o;
        }
        uint32_t ab = run - tot;
        hist[4*lane+3] = ab + h3;
        hist[4*lane+2] = ab + h3 + h2;
        hist[4*lane+1] = ab + h3 + h2 + h1;
        hist[4*lane+0] = ab + tot;
    }
    __syncthreads();
}

// 6-wide row window [c4-1 .. c4+4] from the LDS D-tile (OOB -> -inf).
template<int W>
__device__ __forceinline__ void row6(const float* df, int row, int c4, float* a) {
    const float4 m = ((const float4*)df)[(row * W + c4) >> 2];
    a[1] = m.x; a[2] = m.y; a[3] = m.z; a[4] = m.w;
    a[0] = (c4 > 0)     ? df[row * W + c4 - 1] : -INFINITY;
    a[5] = (c4 + 4 < W) ? df[row * W + c4 + 4] : -INFINITY;
}

// ---- stage 1 body: NMS + D16 radix-select, emit u32 slots ------------------
template<int H, int W, int NS>
__device__ __forceinline__ void stage1_impl(const float* __restrict__ x,
                                            int s, int b,
                                            uint32_t* __restrict__ key_out,
                                            unsigned char* smem)
{
    constexpr int W4 = W / 4;
    constexpr int tileRows = SR + 2;
    const int r0 = s * SR;
    const int rows = (H - r0 < SR) ? (H - r0) : SR;

    float*    df    = (float*)smem;                        // tileRows * W
    uint32_t* surv  = (uint32_t*)(df + tileRows * W);      // CAP
    uint32_t* hist  = surv + CAP;                          // 256
    uint32_t* hist2 = hist + 256;                          // 256 (level-2)
    uint32_t* outb  = hist2 + 256;                         // KSLOT
    __shared__ int s_cnt, s_out;
    __shared__ uint32_t s_bin, s_ab, s_bin2, s_none;
    if (threadIdx.x == 0) { s_cnt = 0; s_out = 0; s_none = 0; }
    if (threadIdx.x < 256) { hist[threadIdx.x] = 0; hist2[threadIdx.x] = 0; }
    if (threadIdx.x < KSLOT) outb[threadIdx.x] = 0;

    const float*  x0  = x + (size_t)b * 2 * H * W;
    const float*  x1  = x0 + (size_t)H * W;
    const float4* x0v = (const float4*)x0;
    const float4* x1v = (const float4*)x1;
    float4* dfv = (float4*)df;

    // D tile (rows r0-1 .. r0+SR), float4-vectorized; OOB rows -> -inf.
    constexpr int nt4 = tileRows * W4;
    for (int t = threadIdx.x; t < nt4; t += TPB) {
        int tr = t / W4, c4 = t - tr * W4;        // compile-time divisor
        int r = r0 - 1 + tr;
        float4 d4 = make_float4(-INFINITY, -INFINITY, -INFINITY, -INFINITY);
        if (r >= 0 && r < H) {
            float4 a = x0v[r * W4 + c4];
            float4 c = x1v[r * W4 + c4];
            d4.x = __fsub_rn(c.x, a.x);
            d4.y = __fsub_rn(c.y, a.y);
            d4.z = __fsub_rn(c.z, a.z);
            d4.w = __fsub_rn(c.w, a.w);
        }
        dfv[t] = d4;
    }
    __syncthreads();

    // NMS (4 cells/iter) + level-1 histogram fused into the keep path.
    // Scaled distinctness certificate replaces the fixed 0.25 window (R14):
    // f64 G_exact now fires ~30x per RUN instead of ~450K.
    const int groups = rows * W4;
    for (int g = threadIdx.x; g < groups; g += TPB) {
        int lr = g / W4, c4 = (g - lr * W4) << 2; // compile-time divisor
        int tr = lr + 1;
        float ap[6], ac[6], an[6];
        row6<W>(df, tr - 1, c4, ap);
        row6<W>(df, tr,     c4, ac);
        row6<W>(df, tr + 1, c4, an);
        #pragma unroll
        for (int j = 0; j < 4; ++j) {
            float v = ac[j + 1];
            float mx = fmaxf(fmaxf(fmaxf(ap[j], ap[j+1]), fmaxf(ap[j+2], an[j])),
                             fmaxf(fmaxf(an[j+1], an[j+2]), fmaxf(ac[j], ac[j+2])));
            float thr = 4e-6f * __expf(fmaxf(mx, 0.0f)); // >=16x (mx>0) / >=4x (mx<=0) margin
            bool keep;
            if (v >= mx) keep = true;                    // exact
            else if (mx - v >= thr) keep = false;        // certified G-distinct
            else keep = (G_exact(v) == G_exact(mx));     // ultra-rare exact tie check
            if (keep) {
                uint32_t key16 = flip_f32(v) >> 16;
                int pos = atomicAdd(&s_cnt, 1);
                if (pos < CAP)
                    surv[pos] = (key16 << 16) | ((uint32_t)lr << 9) | (uint32_t)(c4 + j);
                atomicAdd(&hist[key16 >> 8], 1u);
            }
        }
    }
    __syncthreads();
    const int n = (s_cnt < CAP) ? s_cnt : CAP;

    // Level-1 select on D16 high byte.
    suffix_scan_256(hist);
    if (threadIdx.x < 256) {
        uint32_t si = hist[threadIdx.x];
        uint32_t sn = (threadIdx.x < 255) ? hist[threadIdx.x + 1] : 0u;
        if (threadIdx.x == 0 && si < K1) s_none = 1;
        if (si >= K1 && sn < K1) { s_bin = threadIdx.x; s_ab = sn; }
    }
    __syncthreads();

    uint32_t T16 = 0;
    if (!s_none) {
        const uint32_t b3 = s_bin;
        const uint32_t k2 = K1 - s_ab;
        // Level-2: hist2 pre-zeroed in the init phase (no rezero barrier).
        for (int t = threadIdx.x; t < n; t += TPB) {
            uint32_t sv = surv[t];
            if ((sv >> 24) == b3) atomicAdd(&hist2[(sv >> 16) & 255u], 1u);
        }
        __syncthreads();
        suffix_scan_256(hist2);
        if (threadIdx.x < 256) {
            uint32_t si = hist2[threadIdx.x];
            uint32_t sn = (threadIdx.x < 255) ? hist2[threadIdx.x + 1] : 0u;
            if (si >= k2 && sn < k2) s_bin2 = threadIdx.x;
        }
        __syncthreads();
        T16 = (b3 << 8) | s_bin2;
    }

    // Compact survivors with D16 >= T16 (unsorted) into pre-zeroed outb.
    for (int t = threadIdx.x; t < n; t += TPB) {
        uint32_t sv = surv[t];
        if ((sv >> 16) >= T16) {
            int pos = atomicAdd(&s_out, 1);
            if (pos < KSLOT) outb[pos] = sv;
        }
    }
    __syncthreads();
    if (threadIdx.x < KSLOT)
        key_out[((size_t)b * NS + s) * KSLOT + threadIdx.x] = outb[threadIdx.x];
}

__global__ __launch_bounds__(TPB) void stage1(const float* __restrict__ bmap,
                                              const float* __restrict__ pmap,
                                              uint32_t* __restrict__ bkey,
                                              uint32_t* __restrict__ pkey)
{
    extern __shared__ unsigned char smem[];
    if (blockIdx.x < NSB)
        stage1_impl<HB, WB, NSB>(bmap, blockIdx.x, blockIdx.y, bkey, smem);
    else
        stage1_impl<HP, WP, NSP>(pmap, blockIdx.x - NSB, blockIdx.y, pkey, smem);
}

// ---- stage 2 body: D16 select -> exact-p re-rank of <=256 -> decode --------
template<int H, int W, int NS, bool BALL>
__device__ __forceinline__ void stage2_impl(const float* __restrict__ xmap,
                                            const float* __restrict__ pbbox,
                                            const uint32_t* __restrict__ key_in,
                                            float* __restrict__ outp,
                                            int b, unsigned char* smem)
{
    constexpr int M = NS * KSLOT;
    const float* x0 = xmap + (size_t)b * 2 * H * W;
    const float* x1 = x0 + (size_t)H * W;
    const uint32_t* kin = key_in + (size_t)b * M;

    uint32_t* keys  = (uint32_t*)smem;           // M
    uint32_t* hist  = keys + M;                  // 256 (level-1)
    uint32_t* hist2 = hist + 256;                // 256 (level-2)
    uint32_t* rnk   = hist2 + 256;               // 256 (ranks)
    uint64_t* outb  = (uint64_t*)(rnk + 256);    // 256
    __shared__ int s_out;
    __shared__ uint32_t s_bin, s_ab, s_bin2, s_none;
    if (threadIdx.x == 0) { s_out = 0; s_none = 0; }
    if (threadIdx.x < 256) {
        hist[threadIdx.x] = 0; hist2[threadIdx.x] = 0;
        rnk[threadIdx.x] = 0; outb[threadIdx.x] = 0;
    }
    // Defensive zero of the 100 output rows (rank-scatter fills real rows).
    for (int t = threadIdx.x; t < KTOP * 5; t += TPB) outp[t] = 0.f;
    __syncthreads();

    // Load keys + level-1 histogram in one pass (clustered bin atomics).
    for (int t = threadIdx.x; t < M; t += TPB) {
        uint32_t k = kin[t];
        keys[t] = k;
        hist_clustered(hist, k >> 24, k != 0);
    }
    __syncthreads();
    suffix_scan_256(hist);
    if (threadIdx.x < 256) {
        uint32_t si = hist[threadIdx.x];
        uint32_t sn = (threadIdx.x < 255) ? hist[threadIdx.x + 1] : 0u;
        if (threadIdx.x == 0 && si < K1) s_none = 1;
        if (si >= K1 && sn < K1) { s_bin = threadIdx.x; s_ab = sn; }
    }
    __syncthreads();

    uint32_t T16 = 0;
    if (!s_none) {
        const uint32_t b3 = s_bin;
        const uint32_t k2 = K1 - s_ab;
        // Level-2: hist2 pre-zeroed in the init phase.
        for (int t = threadIdx.x; t < M; t += TPB) {
            uint32_t k = keys[t];
            if (k && (k >> 24) == b3) atomicAdd(&hist2[(k >> 16) & 255u], 1u);
        }
        __syncthreads();
        suffix_scan_256(hist2);
        if (threadIdx.x < 256) {
            uint32_t si = hist2[threadIdx.x];
            uint32_t sn = (threadIdx.x < 255) ? hist2[threadIdx.x + 1] : 0u;
            if (si >= k2 && sn < k2) s_bin2 = threadIdx.x;
        }
        __syncthreads();
        T16 = (b3 << 8) | s_bin2;
    }

    // Compact finalists into pre-zeroed outb; exact np p computed only here.
    for (int t = threadIdx.x; t < M; t += TPB) {
        uint32_t k = keys[t];
        bool take = (k != 0) && ((k >> 16) >= T16);
        int pos = agg_push(&s_out, take);
        if (take && pos < 256) {
            int sIdx = t / KSLOT;                      // compile-time divisor
            int lr = (k >> 9) & 7, c = k & 511;
            int gidx = (sIdx * SR + lr) * W + c;
            float D = __fsub_rn(x1[gidx], x0[gidx]);
            float p = G_exact(D);
            outb[pos] = ((uint64_t)__float_as_uint(p) << 32) | (uint32_t)(~gidx);
        }
    }
    __syncthreads();

    // Rank-by-counting over unique u64 keys (2 barriers vs bitonic's 36).
    {
        int i = threadIdx.x & 255;
        int half = threadIdx.x >> 8;
        uint64_t ki = outb[i];
        uint32_t cnt = 0;
        int j0 = half * 128;
        #pragma unroll 4
        for (int j = j0; j < j0 + 128; ++j) cnt += (outb[j] > ki) ? 1u : 0u;
        atomicAdd(&rnk[i], cnt);
    }
    __syncthreads();

    // Decode: finalist with rank r < KTOP writes output row r directly.
    if (threadIdx.x < 256) {
        uint64_t k = outb[threadIdx.x];
        uint32_t r = rnk[threadIdx.x];
        if (k != 0 && r < KTOP) {
            int id = (int)(~(uint32_t)k);
            float val = __uint_as_float((uint32_t)(k >> 32));
            int yy = id / W, xx = id - yy * W;             // compile-time divisor
            constexpr float ds = BALL ? 4.0f : 16.0f;
            float xc = (float)xx * ds + (ds - 1.0f) * 0.5f;
            float yc = (float)yy * ds + (ds - 1.0f) * 0.5f;
            float t0 = 0.f, t1 = 0.f;
            float t2 = BALL ? 40.0f : 0.0f, t3 = BALL ? 40.0f : 0.0f;
            if (!BALL) {
                const float* bb = pbbox + (size_t)b * 4 * H * W;
                constexpr float sx = (float)W * ds, sy = (float)H * ds;
                t0 = bb[id]             * sx;
                t1 = bb[id + H * W]     * sy;
                t2 = bb[id + 2 * H * W] * sx;
                t3 = bb[id + 3 * H * W] * sy;
            }
            float bx = xc + t0, by = yc + t1;
            float* op = outp + (size_t)r * 5;
            op[0] = bx - 0.5f * t2;
            op[1] = by - 0.5f * t3;
            op[2] = bx + 0.5f * t2;
            op[3] = by + 0.5f * t3;
            op[4] = val;
        }
    }
}

__global__ __launch_bounds__(TPB) void stage2(const float* __restrict__ bmap,
                                              const float* __restrict__ pmap,
                                              const float* __restrict__ pbbox,
                                              const uint32_t* __restrict__ bkey,
                                              const uint32_t* __restrict__ pkey,
                                              float* __restrict__ out)
{
    extern __shared__ unsigned char smem[];
    if (blockIdx.x < NB) {
        int b = blockIdx.x;
        stage2_impl<HB, WB, NSB, true>(bmap, nullptr, bkey,
            out + (size_t)NB * KTOP * 5 + (size_t)b * KTOP * 5, b, smem);
    } else {
        int b = blockIdx.x - NB;
        stage2_impl<HP, WP, NSP, false>(pmap, pbbox, pkey,
            out + (size_t)b * KTOP * 5, b, smem);
    }
}

// ---- launch -----------------------------------------------------------------
extern "C" void kernel_launch(void* const* d_in, const int* in_sizes, int n_in,
                              void* d_out, int out_size, void* d_ws, size_t ws_size,
                              hipStream_t stream) {
    const float* pmap  = (const float*)d_in[0];   // [64,2,68,120]
    const float* pbbox = (const float*)d_in[1];   // [64,4,68,120]
    const float* bmap  = (const float*)d_in[2];   // [64,2,272,480]
    float* out = (float*)d_out;                   // player [64,100,5] then ball

    uint32_t* ws_bkey = (uint32_t*)d_ws;                       // 64*34*192 u32
    uint32_t* ws_pkey = ws_bkey + (size_t)NB * NSB * KSLOT;    // 64*9*192 u32
    // total ws: 2,113,536 B (within proven budget)

    // LDS: df 19200 + surv 3072 + hist 1024 + hist2 1024 + outb 768
    //    = 25088 B -> 4 blk/CU (wave-capped)
    size_t lds1 = (size_t)(SR + 2) * WB * 4 + (size_t)CAP * 4 + 2048 + (size_t)KSLOT * 4;
    stage1<<<dim3(NSB + NSP, NB), TPB, lds1, stream>>>(bmap, pmap, ws_bkey, ws_pkey);

    // LDS: keys 26112 + hist 1024 + hist2 1024 + rnk 1024 + outb 2048 = 31232 B
    size_t lds2 = (size_t)NSB * KSLOT * 4 + 3072 + 2048;
    stage2<<<2 * NB, TPB, lds2, stream>>>(bmap, pmap, pbbox, ws_bkey, ws_pkey, out);
}

// Round 10
// 126.273 us; speedup vs baseline: 1.2347x; 1.0141x over previous
//
#include <hip/hip_runtime.h>
#include <stdint.h>
#include <math.h>

#define TPB   512    // 8 waves/block -> 4 blocks/CU hits the 32-wave cap
#define KTOP  100
#define K1    128    // selection rank cut (per-slice in s1, per-image in s2)
#define KSLOT 192    // per-slice emitted u32 slots (>= K1 + tie-bin margin)
#define CAP   768    // stage-1 survivor capacity (expected ~450/slice, +13 sigma)
#define SR    8      // slice rows

#define HB 272
#define WB 480
#define NSB 34       // 272/8
#define HP 68
#define WP 120
#define NSP 9        // ceil(68/8), last slice 4 rows
#define NB 64

// ============================================================================
// Validated invariants (prior session, absmax 0.0):
//  - np-f32 softmax p is a MONOTONE function G of D = fl32(x1-x0);
//    G collapse window: for mx>0, ~6e-8*e^mx; for mx<=0, bounded by ~1e-6.
//  - NMS: keep iff p >= all 8 neighbors; D-space fast path + exact G on ties.
//  - top-k tie order: (p desc, idx asc)  ==  u64 key (p_bits<<32 | ~idx) desc.
//  - 16-bit D-key rank-128 cut contains the exact top-100 set.
// Ladder: R8 139.4 -> R14 128.1 (scaled tie certificate: distinct if
//  mx-v >= 4e-6*e^max(mx,0); f64 G_exact ~30 calls/run). Post-R14 budget:
//  fills 82 (fixed) + stage1 ~33 + stage2 ~13.
// R15 (all exactness-preserving):
//  - stage2: batched key load (regs + sched_barrier(0) pin) -- 1 blk/CU has
//    nothing to hide the 13 serialized load round-trips behind.
//  - stage1: column-max sharing (vx[i]=max of column i over 3 rows; mx =
//    max(vx[j],vx[j+2],ap[j+1],an[j+1]) -- same 8-value max, bit-identical).
//  - stage1: direct-global emit (zero key_out slots in init phase, scatter
//    in compact; outb LDS + final barrier phase deleted).
// ============================================================================
__device__ __forceinline__ float G_exact(float D) {
    float t = -fabsf(D);
    float etf = (float)exp((double)t);       // correctly-rounded f32 exp
    return (D > 0.0f) ? __fdiv_rn(1.0f, __fadd_rn(etf, 1.0f))
                      : __fdiv_rn(etf, __fadd_rn(1.0f, etf));
}

__device__ __forceinline__ uint32_t flip_f32(float D) {
    uint32_t u = __float_as_uint(D);
    return (u & 0x80000000u) ? ~u : (u | 0x80000000u);
}

// Wave-aggregated counter push (stage2 only: low-frequency call sites).
__device__ __forceinline__ int agg_push(int* ctr, bool active) {
    uint64_t m = __ballot(active);
    int pos = -1;
    if (active) {
        int lane = threadIdx.x & 63;
        int lead = __ffsll((unsigned long long)m) - 1;
        int before = (int)__popcll(m & ((1ull << lane) - 1ull));
        int base = 0;
        if (lane == lead) base = atomicAdd(ctr, (int)__popcll(m));
        base = __shfl(base, lead, 64);
        pos = base + before;
    }
    return pos;
}

// Clustered histogram add (stage2 load pass only): one atomicAdd per
// DISTINCT bin per wave.
__device__ __forceinline__ void hist_clustered(uint32_t* hist, uint32_t bin, bool active) {
    uint64_t todo = __ballot(active);
    while (todo) {
        int lead = __ffsll((unsigned long long)todo) - 1;
        uint32_t b = (uint32_t)__shfl((int)bin, lead, 64);
        uint64_t same = __ballot(active && (bin == b));
        if ((int)(threadIdx.x & 63) == lead) atomicAdd(&hist[b], (uint32_t)__popcll(same));
        todo &= ~same;
    }
}

// In-place suffix-sum of 256 u32 bins: hist[i] <- sum_{j>=i} hist[j].
// Wave 0 via shuffles; ends with a barrier. (validated)
__device__ __forceinline__ void suffix_scan_256(uint32_t* hist) {
    if (threadIdx.x < 64) {
        int lane = threadIdx.x;
        uint32_t h0 = hist[4*lane+0], h1 = hist[4*lane+1];
        uint32_t h2 = hist[4*lane+2], h3 = hist[4*lane+3];
        uint32_t tot = h0 + h1 + h2 + h3;
        uint32_t run = tot;
        #pragma unroll
        for (int d = 1; d < 64; d <<= 1) {
            uint32_t o = __shfl_down(run, d, 64);
            if (lane + d < 64) run += o;
        }
        uint32_t ab = run - tot;
        hist[4*lane+3] = ab + h3;
        hist[4*lane+2] = ab + h3 + h2;
        hist[4*lane+1] = ab + h3 + h2 + h1;
        hist[4*lane+0] = ab + tot;
    }
    __syncthreads();
}

// 6-wide row window [c4-1 .. c4+4] from the LDS D-tile (OOB -> -inf).
template<int W>
__device__ __forceinline__ void row6(const float* df, int row, int c4, float* a) {
    const float4 m = ((const float4*)df)[(row * W + c4) >> 2];
    a[1] = m.x; a[2] = m.y; a[3] = m.z; a[4] = m.w;
    a[0] = (c4 > 0)     ? df[row * W + c4 - 1] : -INFINITY;
    a[5] = (c4 + 4 < W) ? df[row * W + c4 + 4] : -INFINITY;
}

// ---- stage 1 body: NMS + D16 radix-select, emit u32 slots ------------------
template<int H, int W, int NS>
__device__ __forceinline__ void stage1_impl(const float* __restrict__ x,
                                            int s, int b,
                                            uint32_t* __restrict__ key_out,
                                            unsigned char* smem)
{
    constexpr int W4 = W / 4;
    constexpr int tileRows = SR + 2;
    const int r0 = s * SR;
    const int rows = (H - r0 < SR) ? (H - r0) : SR;

    float*    df    = (float*)smem;                        // tileRows * W
    uint32_t* surv  = (uint32_t*)(df + tileRows * W);      // CAP
    uint32_t* hist  = surv + CAP;                          // 256
    uint32_t* hist2 = hist + 256;                          // 256 (level-2)
    __shared__ int s_cnt, s_out;
    __shared__ uint32_t s_bin, s_ab, s_bin2, s_none;
    if (threadIdx.x == 0) { s_cnt = 0; s_out = 0; s_none = 0; }
    if (threadIdx.x < 256) { hist[threadIdx.x] = 0; hist2[threadIdx.x] = 0; }

    // Direct-global emit: zero this slice's KSLOT slots now (overlaps tile
    // load); the compact scatter overwrites [0, s_out) later. Same-block
    // stores separated by barriers -> ordered.
    uint32_t* ko = key_out + ((size_t)b * NS + s) * KSLOT;
    if (threadIdx.x < KSLOT) ko[threadIdx.x] = 0u;

    const float*  x0  = x + (size_t)b * 2 * H * W;
    const float*  x1  = x0 + (size_t)H * W;
    const float4* x0v = (const float4*)x0;
    const float4* x1v = (const float4*)x1;
    float4* dfv = (float4*)df;

    // D tile (rows r0-1 .. r0+SR), float4-vectorized; OOB rows -> -inf.
    constexpr int nt4 = tileRows * W4;
    for (int t = threadIdx.x; t < nt4; t += TPB) {
        int tr = t / W4, c4 = t - tr * W4;        // compile-time divisor
        int r = r0 - 1 + tr;
        float4 d4 = make_float4(-INFINITY, -INFINITY, -INFINITY, -INFINITY);
        if (r >= 0 && r < H) {
            float4 a = x0v[r * W4 + c4];
            float4 c = x1v[r * W4 + c4];
            d4.x = __fsub_rn(c.x, a.x);
            d4.y = __fsub_rn(c.y, a.y);
            d4.z = __fsub_rn(c.z, a.z);
            d4.w = __fsub_rn(c.w, a.w);
        }
        dfv[t] = d4;
    }
    __syncthreads();

    // NMS (4 cells/iter) + level-1 histogram fused into the keep path.
    // Column-max sharing: vx[i] = max over 3 rows of column i (bit-identical
    // 8-neighbor max, fewer ops). Scaled tie certificate (R14).
    const int groups = rows * W4;
    for (int g = threadIdx.x; g < groups; g += TPB) {
        int lr = g / W4, c4 = (g - lr * W4) << 2; // compile-time divisor
        int tr = lr + 1;
        float ap[6], ac[6], an[6], vx[6];
        row6<W>(df, tr - 1, c4, ap);
        row6<W>(df, tr,     c4, ac);
        row6<W>(df, tr + 1, c4, an);
        #pragma unroll
        for (int i = 0; i < 6; ++i) vx[i] = fmaxf(fmaxf(ap[i], an[i]), ac[i]);
        #pragma unroll
        for (int j = 0; j < 4; ++j) {
            float v = ac[j + 1];
            float mx = fmaxf(fmaxf(fmaxf(vx[j], vx[j+2]), ap[j+1]), an[j+1]);
            float thr = 4e-6f * __expf(fmaxf(mx, 0.0f)); // >=16x/4x margin certificate
            bool keep;
            if (v >= mx) keep = true;                    // exact
            else if (mx - v >= thr) keep = false;        // certified G-distinct
            else keep = (G_exact(v) == G_exact(mx));     // ultra-rare exact tie check
            if (keep) {
                uint32_t key16 = flip_f32(v) >> 16;
                int pos = atomicAdd(&s_cnt, 1);
                if (pos < CAP)
                    surv[pos] = (key16 << 16) | ((uint32_t)lr << 9) | (uint32_t)(c4 + j);
                atomicAdd(&hist[key16 >> 8], 1u);
            }
        }
    }
    __syncthreads();
    const int n = (s_cnt < CAP) ? s_cnt : CAP;

    // Level-1 select on D16 high byte.
    suffix_scan_256(hist);
    if (threadIdx.x < 256) {
        uint32_t si = hist[threadIdx.x];
        uint32_t sn = (threadIdx.x < 255) ? hist[threadIdx.x + 1] : 0u;
        if (threadIdx.x == 0 && si < K1) s_none = 1;
        if (si >= K1 && sn < K1) { s_bin = threadIdx.x; s_ab = sn; }
    }
    __syncthreads();

    uint32_t T16 = 0;
    if (!s_none) {
        const uint32_t b3 = s_bin;
        const uint32_t k2 = K1 - s_ab;
        // Level-2: hist2 pre-zeroed in the init phase (no rezero barrier).
        for (int t = threadIdx.x; t < n; t += TPB) {
            uint32_t sv = surv[t];
            if ((sv >> 24) == b3) atomicAdd(&hist2[(sv >> 16) & 255u], 1u);
        }
        __syncthreads();
        suffix_scan_256(hist2);
        if (threadIdx.x < 256) {
            uint32_t si = hist2[threadIdx.x];
            uint32_t sn = (threadIdx.x < 255) ? hist2[threadIdx.x + 1] : 0u;
            if (si >= k2 && sn < k2) s_bin2 = threadIdx.x;
        }
        __syncthreads();
        T16 = (b3 << 8) | s_bin2;
    }

    // Compact survivors with D16 >= T16: scatter directly to global
    // (slots pre-zeroed in init; no trailing barrier/copy phase needed).
    for (int t = threadIdx.x; t < n; t += TPB) {
        uint32_t sv = surv[t];
        if ((sv >> 16) >= T16) {
            int pos = atomicAdd(&s_out, 1);
            if (pos < KSLOT) ko[pos] = sv;
        }
    }
}

__global__ __launch_bounds__(TPB) void stage1(const float* __restrict__ bmap,
                                              const float* __restrict__ pmap,
                                              uint32_t* __restrict__ bkey,
                                              uint32_t* __restrict__ pkey)
{
    extern __shared__ unsigned char smem[];
    if (blockIdx.x < NSB)
        stage1_impl<HB, WB, NSB>(bmap, blockIdx.x, blockIdx.y, bkey, smem);
    else
        stage1_impl<HP, WP, NSP>(pmap, blockIdx.x - NSB, blockIdx.y, pkey, smem);
}

// ---- stage 2 body: D16 select -> exact-p re-rank of <=256 -> decode --------
template<int H, int W, int NS, bool BALL>
__device__ __forceinline__ void stage2_impl(const float* __restrict__ xmap,
                                            const float* __restrict__ pbbox,
                                            const uint32_t* __restrict__ key_in,
                                            float* __restrict__ outp,
                                            int b, unsigned char* smem)
{
    constexpr int M = NS * KSLOT;
    const float* x0 = xmap + (size_t)b * 2 * H * W;
    const float* x1 = x0 + (size_t)H * W;
    const uint32_t* kin = key_in + (size_t)b * M;

    uint32_t* keys  = (uint32_t*)smem;           // M
    uint32_t* hist  = keys + M;                  // 256 (level-1)
    uint32_t* hist2 = hist + 256;                // 256 (level-2)
    uint32_t* rnk   = hist2 + 256;               // 256 (ranks)
    uint64_t* outb  = (uint64_t*)(rnk + 256);    // 256
    __shared__ int s_out;
    __shared__ uint32_t s_bin, s_ab, s_bin2, s_none;
    if (threadIdx.x == 0) { s_out = 0; s_none = 0; }
    if (threadIdx.x < 256) {
        hist[threadIdx.x] = 0; hist2[threadIdx.x] = 0;
        rnk[threadIdx.x] = 0; outb[threadIdx.x] = 0;
    }
    // Defensive zero of the 100 output rows (rank-scatter fills real rows).
    for (int t = threadIdx.x; t < KTOP * 5; t += TPB) outp[t] = 0.f;
    __syncthreads();

    // Batched key load: issue ALL global loads into registers before any use
    // (sched_barrier(0) pins issue order -- at 1 block/CU there is no other
    // wave to hide the serialized round-trips behind). Then LDS store + hist.
    {
        constexpr int NLD = (M + TPB - 1) / TPB;
        uint32_t kr[NLD];
        #pragma unroll
        for (int u = 0; u < NLD; ++u) {
            int t = threadIdx.x + u * TPB;
            kr[u] = (t < M) ? kin[t] : 0u;
        }
        __builtin_amdgcn_sched_barrier(0);
        #pragma unroll
        for (int u = 0; u < NLD; ++u) {
            int t = threadIdx.x + u * TPB;
            if (t < M) keys[t] = kr[u];
            hist_clustered(hist, kr[u] >> 24, (t < M) && (kr[u] != 0u));
        }
    }
    __syncthreads();
    suffix_scan_256(hist);
    if (threadIdx.x < 256) {
        uint32_t si = hist[threadIdx.x];
        uint32_t sn = (threadIdx.x < 255) ? hist[threadIdx.x + 1] : 0u;
        if (threadIdx.x == 0 && si < K1) s_none = 1;
        if (si >= K1 && sn < K1) { s_bin = threadIdx.x; s_ab = sn; }
    }
    __syncthreads();

    uint32_t T16 = 0;
    if (!s_none) {
        const uint32_t b3 = s_bin;
        const uint32_t k2 = K1 - s_ab;
        // Level-2: hist2 pre-zeroed in the init phase.
        for (int t = threadIdx.x; t < M; t += TPB) {
            uint32_t k = keys[t];
            if (k && (k >> 24) == b3) atomicAdd(&hist2[(k >> 16) & 255u], 1u);
        }
        __syncthreads();
        suffix_scan_256(hist2);
        if (threadIdx.x < 256) {
            uint32_t si = hist2[threadIdx.x];
            uint32_t sn = (threadIdx.x < 255) ? hist2[threadIdx.x + 1] : 0u;
            if (si >= k2 && sn < k2) s_bin2 = threadIdx.x;
        }
        __syncthreads();
        T16 = (b3 << 8) | s_bin2;
    }

    // Compact finalists into pre-zeroed outb; exact np p computed only here.
    for (int t = threadIdx.x; t < M; t += TPB) {
        uint32_t k = keys[t];
        bool take = (k != 0) && ((k >> 16) >= T16);
        int pos = agg_push(&s_out, take);
        if (take && pos < 256) {
            int sIdx = t / KSLOT;                      // compile-time divisor
            int lr = (k >> 9) & 7, c = k & 511;
            int gidx = (sIdx * SR + lr) * W + c;
            float D = __fsub_rn(x1[gidx], x0[gidx]);
            float p = G_exact(D);
            outb[pos] = ((uint64_t)__float_as_uint(p) << 32) | (uint32_t)(~gidx);
        }
    }
    __syncthreads();

    // Rank-by-counting over unique u64 keys (2 barriers vs bitonic's 36).
    {
        int i = threadIdx.x & 255;
        int half = threadIdx.x >> 8;
        uint64_t ki = outb[i];
        uint32_t cnt = 0;
        int j0 = half * 128;
        #pragma unroll 4
        for (int j = j0; j < j0 + 128; ++j) cnt += (outb[j] > ki) ? 1u : 0u;
        atomicAdd(&rnk[i], cnt);
    }
    __syncthreads();

    // Decode: finalist with rank r < KTOP writes output row r directly.
    if (threadIdx.x < 256) {
        uint64_t k = outb[threadIdx.x];
        uint32_t r = rnk[threadIdx.x];
        if (k != 0 && r < KTOP) {
            int id = (int)(~(uint32_t)k);
            float val = __uint_as_float((uint32_t)(k >> 32));
            int yy = id / W, xx = id - yy * W;             // compile-time divisor
            constexpr float ds = BALL ? 4.0f : 16.0f;
            float xc = (float)xx * ds + (ds - 1.0f) * 0.5f;
            float yc = (float)yy * ds + (ds - 1.0f) * 0.5f;
            float t0 = 0.f, t1 = 0.f;
            float t2 = BALL ? 40.0f : 0.0f, t3 = BALL ? 40.0f : 0.0f;
            if (!BALL) {
                const float* bb = pbbox + (size_t)b * 4 * H * W;
                constexpr float sx = (float)W * ds, sy = (float)H * ds;
                t0 = bb[id]             * sx;
                t1 = bb[id + H * W]     * sy;
                t2 = bb[id + 2 * H * W] * sx;
                t3 = bb[id + 3 * H * W] * sy;
            }
            float bx = xc + t0, by = yc + t1;
            float* op = outp + (size_t)r * 5;
            op[0] = bx - 0.5f * t2;
            op[1] = by - 0.5f * t3;
            op[2] = bx + 0.5f * t2;
            op[3] = by + 0.5f * t3;
            op[4] = val;
        }
    }
}

__global__ __launch_bounds__(TPB) void stage2(const float* __restrict__ bmap,
                                              const float* __restrict__ pmap,
                                              const float* __restrict__ pbbox,
                                              const uint32_t* __restrict__ bkey,
                                              const uint32_t* __restrict__ pkey,
                                              float* __restrict__ out)
{
    extern __shared__ unsigned char smem[];
    if (blockIdx.x < NB) {
        int b = blockIdx.x;
        stage2_impl<HB, WB, NSB, true>(bmap, nullptr, bkey,
            out + (size_t)NB * KTOP * 5 + (size_t)b * KTOP * 5, b, smem);
    } else {
        int b = blockIdx.x - NB;
        stage2_impl<HP, WP, NSP, false>(pmap, pbbox, pkey,
            out + (size_t)b * KTOP * 5, b, smem);
    }
}

// ---- launch -----------------------------------------------------------------
extern "C" void kernel_launch(void* const* d_in, const int* in_sizes, int n_in,
                              void* d_out, int out_size, void* d_ws, size_t ws_size,
                              hipStream_t stream) {
    const float* pmap  = (const float*)d_in[0];   // [64,2,68,120]
    const float* pbbox = (const float*)d_in[1];   // [64,4,68,120]
    const float* bmap  = (const float*)d_in[2];   // [64,2,272,480]
    float* out = (float*)d_out;                   // player [64,100,5] then ball

    uint32_t* ws_bkey = (uint32_t*)d_ws;                       // 64*34*192 u32
    uint32_t* ws_pkey = ws_bkey + (size_t)NB * NSB * KSLOT;    // 64*9*192 u32
    // total ws: 2,113,536 B (within proven budget)

    // LDS: df 19200 + surv 3072 + hist 1024 + hist2 1024 = 24320 B -> 4 blk/CU
    size_t lds1 = (size_t)(SR + 2) * WB * 4 + (size_t)CAP * 4 + 2048;
    stage1<<<dim3(NSB + NSP, NB), TPB, lds1, stream>>>(bmap, pmap, ws_bkey, ws_pkey);

    // LDS: keys 26112 + hist 1024 + hist2 1024 + rnk 1024 + outb 2048 = 31232 B
    size_t lds2 = (size_t)NSB * KSLOT * 4 + 3072 + 2048;
    stage2<<<2 * NB, TPB, lds2, stream>>>(bmap, pmap, pbbox, ws_bkey, ws_pkey, out);
}

// Round 11
// 125.875 us; speedup vs baseline: 1.2386x; 1.0032x over previous
//
#include <hip/hip_runtime.h>
#include <stdint.h>
#include <math.h>

#define TPB   512    // 8 waves/block
#define KTOP  100
#define K1    128    // selection rank cut (per-slice in s1, per-image in s2)
#define KSLOT 256    // per-slice emitted u32 slots (K1 + fat tie-bin margin)
#define CAP   1536   // stage-1 survivor capacity (~855 expected/slice, +24 sigma)
#define SR    16     // slice rows (R16: 8 -> 16; halves rounds & barrier chains)

#define HB 272
#define WB 480
#define NSB 17       // 272/16
#define HP 68
#define WP 120
#define NSP 5        // ceil(68/16), last slice 4 rows
#define NB 64

// ============================================================================
// Validated invariants (prior session, absmax 0.0):
//  - np-f32 softmax p is a MONOTONE function G of D = fl32(x1-x0);
//    G collapse window: for mx>0, ~6e-8*e^mx; for mx<=0, bounded by ~1e-6.
//  - NMS: keep iff p >= all 8 neighbors; D-space fast path + exact G on ties.
//  - top-k tie order: (p desc, idx asc)  ==  u64 key (p_bits<<32 | ~idx) desc.
//  - per-slice D16 rank-128 cut contains the slice's exact top-100 (slicing-
//    invariant containment: slice members of the image top-100 have per-slice
//    exact rank <= 100 <= K1; data has |D| <= ~9, far from p-collapse regime).
// Ladder: R8 139.4 -> R14 128.1 (scaled tie certificate; f64 G_exact ~30
//  calls/run) -> R15 126.3 (col-max sharing, direct-global emit, stage2
//  batched key load). Budget now: fills ~83 (fixed) + stage1 ~31 + stage2 ~12.
// R16: SR 8->16. Ball 34->17 slices, grid 2752->1408 blocks -> 1.83 rounds
//  (was 2.69); halo fetch -9%; barrier-convoy count halved; stage2 ball M
//  6528->4352. CAP 1536 (+24sigma), KSLOT 256 (tie-bin overflow needs a
//  129-way 16-bit-key collision -- impossible here), lr field 4 bits.
// ============================================================================
__device__ __forceinline__ float G_exact(float D) {
    float t = -fabsf(D);
    float etf = (float)exp((double)t);       // correctly-rounded f32 exp
    return (D > 0.0f) ? __fdiv_rn(1.0f, __fadd_rn(etf, 1.0f))
                      : __fdiv_rn(etf, __fadd_rn(1.0f, etf));
}

__device__ __forceinline__ uint32_t flip_f32(float D) {
    uint32_t u = __float_as_uint(D);
    return (u & 0x80000000u) ? ~u : (u | 0x80000000u);
}

// Wave-aggregated counter push (stage2 only: low-frequency call sites).
__device__ __forceinline__ int agg_push(int* ctr, bool active) {
    uint64_t m = __ballot(active);
    int pos = -1;
    if (active) {
        int lane = threadIdx.x & 63;
        int lead = __ffsll((unsigned long long)m) - 1;
        int before = (int)__popcll(m & ((1ull << lane) - 1ull));
        int base = 0;
        if (lane == lead) base = atomicAdd(ctr, (int)__popcll(m));
        base = __shfl(base, lead, 64);
        pos = base + before;
    }
    return pos;
}

// Clustered histogram add (stage2 load pass only): one atomicAdd per
// DISTINCT bin per wave.
__device__ __forceinline__ void hist_clustered(uint32_t* hist, uint32_t bin, bool active) {
    uint64_t todo = __ballot(active);
    while (todo) {
        int lead = __ffsll((unsigned long long)todo) - 1;
        uint32_t b = (uint32_t)__shfl((int)bin, lead, 64);
        uint64_t same = __ballot(active && (bin == b));
        if ((int)(threadIdx.x & 63) == lead) atomicAdd(&hist[b], (uint32_t)__popcll(same));
        todo &= ~same;
    }
}

// In-place suffix-sum of 256 u32 bins: hist[i] <- sum_{j>=i} hist[j].
// Wave 0 via shuffles; ends with a barrier. (validated)
__device__ __forceinline__ void suffix_scan_256(uint32_t* hist) {
    if (threadIdx.x < 64) {
        int lane = threadIdx.x;
        uint32_t h0 = hist[4*lane+0], h1 = hist[4*lane+1];
        uint32_t h2 = hist[4*lane+2], h3 = hist[4*lane+3];
        uint32_t tot = h0 + h1 + h2 + h3;
        uint32_t run = tot;
        #pragma unroll
        for (int d = 1; d < 64; d <<= 1) {
            uint32_t o = __shfl_down(run, d, 64);
            if (lane + d < 64) run += o;
        }
        uint32_t ab = run - tot;
        hist[4*lane+3] = ab + h3;
        hist[4*lane+2] = ab + h3 + h2;
        hist[4*lane+1] = ab + h3 + h2 + h1;
        hist[4*lane+0] = ab + tot;
    }
    __syncthreads();
}

// 6-wide row window [c4-1 .. c4+4] from the LDS D-tile (OOB -> -inf).
template<int W>
__device__ __forceinline__ void row6(const float* df, int row, int c4, float* a) {
    const float4 m = ((const float4*)df)[(row * W + c4) >> 2];
    a[1] = m.x; a[2] = m.y; a[3] = m.z; a[4] = m.w;
    a[0] = (c4 > 0)     ? df[row * W + c4 - 1] : -INFINITY;
    a[5] = (c4 + 4 < W) ? df[row * W + c4 + 4] : -INFINITY;
}

// ---- stage 1 body: NMS + D16 radix-select, emit u32 slots ------------------
template<int H, int W, int NS>
__device__ __forceinline__ void stage1_impl(const float* __restrict__ x,
                                            int s, int b,
                                            uint32_t* __restrict__ key_out,
                                            unsigned char* smem)
{
    constexpr int W4 = W / 4;
    constexpr int tileRows = SR + 2;
    const int r0 = s * SR;
    const int rows = (H - r0 < SR) ? (H - r0) : SR;

    float*    df    = (float*)smem;                        // tileRows * W
    uint32_t* surv  = (uint32_t*)(df + tileRows * W);      // CAP
    uint32_t* hist  = surv + CAP;                          // 256
    uint32_t* hist2 = hist + 256;                          // 256 (level-2)
    __shared__ int s_cnt, s_out;
    __shared__ uint32_t s_bin, s_ab, s_bin2, s_none;
    if (threadIdx.x == 0) { s_cnt = 0; s_out = 0; s_none = 0; }
    if (threadIdx.x < 256) { hist[threadIdx.x] = 0; hist2[threadIdx.x] = 0; }

    // Direct-global emit: zero this slice's KSLOT slots now (overlaps tile
    // load); the compact scatter overwrites [0, s_out) later.
    uint32_t* ko = key_out + ((size_t)b * NS + s) * KSLOT;
    if (threadIdx.x < KSLOT) ko[threadIdx.x] = 0u;

    const float*  x0  = x + (size_t)b * 2 * H * W;
    const float*  x1  = x0 + (size_t)H * W;
    const float4* x0v = (const float4*)x0;
    const float4* x1v = (const float4*)x1;
    float4* dfv = (float4*)df;

    // D tile (rows r0-1 .. r0+SR), float4-vectorized; OOB rows -> -inf.
    constexpr int nt4 = tileRows * W4;
    for (int t = threadIdx.x; t < nt4; t += TPB) {
        int tr = t / W4, c4 = t - tr * W4;        // compile-time divisor
        int r = r0 - 1 + tr;
        float4 d4 = make_float4(-INFINITY, -INFINITY, -INFINITY, -INFINITY);
        if (r >= 0 && r < H) {
            float4 a = x0v[r * W4 + c4];
            float4 c = x1v[r * W4 + c4];
            d4.x = __fsub_rn(c.x, a.x);
            d4.y = __fsub_rn(c.y, a.y);
            d4.z = __fsub_rn(c.z, a.z);
            d4.w = __fsub_rn(c.w, a.w);
        }
        dfv[t] = d4;
    }
    __syncthreads();

    // NMS (4 cells/iter) + level-1 histogram fused into the keep path.
    // Column-max sharing (bit-identical 8-neighbor max); R14 scaled tie
    // certificate -> f64 G_exact fires ~30x per RUN.
    const int groups = rows * W4;
    for (int g = threadIdx.x; g < groups; g += TPB) {
        int lr = g / W4, c4 = (g - lr * W4) << 2; // compile-time divisor
        int tr = lr + 1;
        float ap[6], ac[6], an[6], vx[6];
        row6<W>(df, tr - 1, c4, ap);
        row6<W>(df, tr,     c4, ac);
        row6<W>(df, tr + 1, c4, an);
        #pragma unroll
        for (int i = 0; i < 6; ++i) vx[i] = fmaxf(fmaxf(ap[i], an[i]), ac[i]);
        #pragma unroll
        for (int j = 0; j < 4; ++j) {
            float v = ac[j + 1];
            float mx = fmaxf(fmaxf(fmaxf(vx[j], vx[j+2]), ap[j+1]), an[j+1]);
            float thr = 4e-6f * __expf(fmaxf(mx, 0.0f)); // >=16x/4x margin certificate
            bool keep;
            if (v >= mx) keep = true;                    // exact
            else if (mx - v >= thr) keep = false;        // certified G-distinct
            else keep = (G_exact(v) == G_exact(mx));     // ultra-rare exact tie check
            if (keep) {
                uint32_t key16 = flip_f32(v) >> 16;
                int pos = atomicAdd(&s_cnt, 1);
                if (pos < CAP)
                    surv[pos] = (key16 << 16) | ((uint32_t)lr << 9) | (uint32_t)(c4 + j);
                atomicAdd(&hist[key16 >> 8], 1u);
            }
        }
    }
    __syncthreads();
    const int n = (s_cnt < CAP) ? s_cnt : CAP;

    // Level-1 select on D16 high byte.
    suffix_scan_256(hist);
    if (threadIdx.x < 256) {
        uint32_t si = hist[threadIdx.x];
        uint32_t sn = (threadIdx.x < 255) ? hist[threadIdx.x + 1] : 0u;
        if (threadIdx.x == 0 && si < K1) s_none = 1;
        if (si >= K1 && sn < K1) { s_bin = threadIdx.x; s_ab = sn; }
    }
    __syncthreads();

    uint32_t T16 = 0;
    if (!s_none) {
        const uint32_t b3 = s_bin;
        const uint32_t k2 = K1 - s_ab;
        // Level-2: hist2 pre-zeroed in the init phase (no rezero barrier).
        for (int t = threadIdx.x; t < n; t += TPB) {
            uint32_t sv = surv[t];
            if ((sv >> 24) == b3) atomicAdd(&hist2[(sv >> 16) & 255u], 1u);
        }
        __syncthreads();
        suffix_scan_256(hist2);
        if (threadIdx.x < 256) {
            uint32_t si = hist2[threadIdx.x];
            uint32_t sn = (threadIdx.x < 255) ? hist2[threadIdx.x + 1] : 0u;
            if (si >= k2 && sn < k2) s_bin2 = threadIdx.x;
        }
        __syncthreads();
        T16 = (b3 << 8) | s_bin2;
    }

    // Compact survivors with D16 >= T16: scatter directly to global.
    for (int t = threadIdx.x; t < n; t += TPB) {
        uint32_t sv = surv[t];
        if ((sv >> 16) >= T16) {
            int pos = atomicAdd(&s_out, 1);
            if (pos < KSLOT) ko[pos] = sv;
        }
    }
}

__global__ __launch_bounds__(TPB) void stage1(const float* __restrict__ bmap,
                                              const float* __restrict__ pmap,
                                              uint32_t* __restrict__ bkey,
                                              uint32_t* __restrict__ pkey)
{
    extern __shared__ unsigned char smem[];
    if (blockIdx.x < NSB)
        stage1_impl<HB, WB, NSB>(bmap, blockIdx.x, blockIdx.y, bkey, smem);
    else
        stage1_impl<HP, WP, NSP>(pmap, blockIdx.x - NSB, blockIdx.y, pkey, smem);
}

// ---- stage 2 body: D16 select -> exact-p re-rank of <=256 -> decode --------
template<int H, int W, int NS, bool BALL>
__device__ __forceinline__ void stage2_impl(const float* __restrict__ xmap,
                                            const float* __restrict__ pbbox,
                                            const uint32_t* __restrict__ key_in,
                                            float* __restrict__ outp,
                                            int b, unsigned char* smem)
{
    constexpr int M = NS * KSLOT;
    const float* x0 = xmap + (size_t)b * 2 * H * W;
    const float* x1 = x0 + (size_t)H * W;
    const uint32_t* kin = key_in + (size_t)b * M;

    uint32_t* keys  = (uint32_t*)smem;           // M
    uint32_t* hist  = keys + M;                  // 256 (level-1)
    uint32_t* hist2 = hist + 256;                // 256 (level-2)
    uint32_t* rnk   = hist2 + 256;               // 256 (ranks)
    uint64_t* outb  = (uint64_t*)(rnk + 256);    // 256
    __shared__ int s_out;
    __shared__ uint32_t s_bin, s_ab, s_bin2, s_none;
    if (threadIdx.x == 0) { s_out = 0; s_none = 0; }
    if (threadIdx.x < 256) {
        hist[threadIdx.x] = 0; hist2[threadIdx.x] = 0;
        rnk[threadIdx.x] = 0; outb[threadIdx.x] = 0;
    }
    // Defensive zero of the 100 output rows (rank-scatter fills real rows).
    for (int t = threadIdx.x; t < KTOP * 5; t += TPB) outp[t] = 0.f;
    __syncthreads();

    // Batched key load: issue ALL global loads into registers before any use
    // (sched_barrier(0) pins issue order -- 1 blk/CU has nothing else to
    // hide the serialized round-trips behind). Then LDS store + hist.
    {
        constexpr int NLD = (M + TPB - 1) / TPB;
        uint32_t kr[NLD];
        #pragma unroll
        for (int u = 0; u < NLD; ++u) {
            int t = threadIdx.x + u * TPB;
            kr[u] = (t < M) ? kin[t] : 0u;
        }
        __builtin_amdgcn_sched_barrier(0);
        #pragma unroll
        for (int u = 0; u < NLD; ++u) {
            int t = threadIdx.x + u * TPB;
            if (t < M) keys[t] = kr[u];
            hist_clustered(hist, kr[u] >> 24, (t < M) && (kr[u] != 0u));
        }
    }
    __syncthreads();
    suffix_scan_256(hist);
    if (threadIdx.x < 256) {
        uint32_t si = hist[threadIdx.x];
        uint32_t sn = (threadIdx.x < 255) ? hist[threadIdx.x + 1] : 0u;
        if (threadIdx.x == 0 && si < K1) s_none = 1;
        if (si >= K1 && sn < K1) { s_bin = threadIdx.x; s_ab = sn; }
    }
    __syncthreads();

    uint32_t T16 = 0;
    if (!s_none) {
        const uint32_t b3 = s_bin;
        const uint32_t k2 = K1 - s_ab;
        // Level-2: hist2 pre-zeroed in the init phase.
        for (int t = threadIdx.x; t < M; t += TPB) {
            uint32_t k = keys[t];
            if (k && (k >> 24) == b3) atomicAdd(&hist2[(k >> 16) & 255u], 1u);
        }
        __syncthreads();
        suffix_scan_256(hist2);
        if (threadIdx.x < 256) {
            uint32_t si = hist2[threadIdx.x];
            uint32_t sn = (threadIdx.x < 255) ? hist2[threadIdx.x + 1] : 0u;
            if (si >= k2 && sn < k2) s_bin2 = threadIdx.x;
        }
        __syncthreads();
        T16 = (b3 << 8) | s_bin2;
    }

    // Compact finalists into pre-zeroed outb; exact np p computed only here.
    for (int t = threadIdx.x; t < M; t += TPB) {
        uint32_t k = keys[t];
        bool take = (k != 0) && ((k >> 16) >= T16);
        int pos = agg_push(&s_out, take);
        if (take && pos < 256) {
            int sIdx = t / KSLOT;                      // compile-time divisor
            int lr = (k >> 9) & 15, c = k & 511;       // lr: 4 bits (SR=16)
            int gidx = (sIdx * SR + lr) * W + c;
            float D = __fsub_rn(x1[gidx], x0[gidx]);
            float p = G_exact(D);
            outb[pos] = ((uint64_t)__float_as_uint(p) << 32) | (uint32_t)(~gidx);
        }
    }
    __syncthreads();

    // Rank-by-counting over unique u64 keys (2 barriers vs bitonic's 36).
    {
        int i = threadIdx.x & 255;
        int half = threadIdx.x >> 8;
        uint64_t ki = outb[i];
        uint32_t cnt = 0;
        int j0 = half * 128;
        #pragma unroll 4
        for (int j = j0; j < j0 + 128; ++j) cnt += (outb[j] > ki) ? 1u : 0u;
        atomicAdd(&rnk[i], cnt);
    }
    __syncthreads();

    // Decode: finalist with rank r < KTOP writes output row r directly.
    if (threadIdx.x < 256) {
        uint64_t k = outb[threadIdx.x];
        uint32_t r = rnk[threadIdx.x];
        if (k != 0 && r < KTOP) {
            int id = (int)(~(uint32_t)k);
            float val = __uint_as_float((uint32_t)(k >> 32));
            int yy = id / W, xx = id - yy * W;             // compile-time divisor
            constexpr float ds = BALL ? 4.0f : 16.0f;
            float xc = (float)xx * ds + (ds - 1.0f) * 0.5f;
            float yc = (float)yy * ds + (ds - 1.0f) * 0.5f;
            float t0 = 0.f, t1 = 0.f;
            float t2 = BALL ? 40.0f : 0.0f, t3 = BALL ? 40.0f : 0.0f;
            if (!BALL) {
                const float* bb = pbbox + (size_t)b * 4 * H * W;
                constexpr float sx = (float)W * ds, sy = (float)H * ds;
                t0 = bb[id]             * sx;
                t1 = bb[id + H * W]     * sy;
                t2 = bb[id + 2 * H * W] * sx;
                t3 = bb[id + 3 * H * W] * sy;
            }
            float bx = xc + t0, by = yc + t1;
            float* op = outp + (size_t)r * 5;
            op[0] = bx - 0.5f * t2;
            op[1] = by - 0.5f * t3;
            op[2] = bx + 0.5f * t2;
            op[3] = by + 0.5f * t3;
            op[4] = val;
        }
    }
}

__global__ __launch_bounds__(TPB) void stage2(const float* __restrict__ bmap,
                                              const float* __restrict__ pmap,
                                              const float* __restrict__ pbbox,
                                              const uint32_t* __restrict__ bkey,
                                              const uint32_t* __restrict__ pkey,
                                              float* __restrict__ out)
{
    extern __shared__ unsigned char smem[];
    if (blockIdx.x < NB) {
        int b = blockIdx.x;
        stage2_impl<HB, WB, NSB, true>(bmap, nullptr, bkey,
            out + (size_t)NB * KTOP * 5 + (size_t)b * KTOP * 5, b, smem);
    } else {
        int b = blockIdx.x - NB;
        stage2_impl<HP, WP, NSP, false>(pmap, pbbox, pkey,
            out + (size_t)b * KTOP * 5, b, smem);
    }
}

// ---- launch -----------------------------------------------------------------
extern "C" void kernel_launch(void* const* d_in, const int* in_sizes, int n_in,
                              void* d_out, int out_size, void* d_ws, size_t ws_size,
                              hipStream_t stream) {
    const float* pmap  = (const float*)d_in[0];   // [64,2,68,120]
    const float* pbbox = (const float*)d_in[1];   // [64,4,68,120]
    const float* bmap  = (const float*)d_in[2];   // [64,2,272,480]
    float* out = (float*)d_out;                   // player [64,100,5] then ball

    uint32_t* ws_bkey = (uint32_t*)d_ws;                       // 64*17*256 u32
    uint32_t* ws_pkey = ws_bkey + (size_t)NB * NSB * KSLOT;    // 64*5*256 u32
    // total ws: 1,441,792 B (within proven budget)

    // LDS: df 18*480*4=34560 + surv 6144 + hist 1024 + hist2 1024 = 42752 B
    //   -> 3 blk/CU (LDS-limited); grid 22x64=1408 blocks -> 1.83 rounds
    size_t lds1 = (size_t)(SR + 2) * WB * 4 + (size_t)CAP * 4 + 2048;
    stage1<<<dim3(NSB + NSP, NB), TPB, lds1, stream>>>(bmap, pmap, ws_bkey, ws_pkey);

    // LDS: keys 17*256*4=17408 + hist 1024 + hist2 1024 + rnk 1024 + outb 2048
    //    = 22528 B
    size_t lds2 = (size_t)NSB * KSLOT * 4 + 3072 + 2048;
    stage2<<<2 * NB, TPB, lds2, stream>>>(bmap, pmap, pbbox, ws_bkey, ws_pkey, out);
}